// Round 18
// baseline (1223.941 us; speedup 1.0000x reference)
//
#include <hip/hip_runtime.h>

// ---------------------------------------------------------------------------
// VolumeAttention: 4 feature levels x 6 decoder depths, B=4, NQ=100, C=256, H=8
// Round 18 = round 17 + kv8 granularity split:
//  - gemm_kv8: 32-token m-tiles (was 64), grid 2720 (was 1360), acc[4][2],
//    K LDS [32][264]=16.5KB, V LDS [256][40]=20KB. Same math per element;
//    halves block duration to shrink the 1360/1024-residency tail.
//  - Everything else identical to round 17 (1216 us verified).
// ---------------------------------------------------------------------------

#define DI __device__ __forceinline__
#define MFMA16(a, b, c) __builtin_amdgcn_mfma_f32_16x16x32_bf16(a, b, c, 0, 0, 0)

typedef __attribute__((ext_vector_type(8))) short bf16x8;
typedef __attribute__((ext_vector_type(8))) unsigned short u16x8;
typedef __attribute__((ext_vector_type(4))) float f32x4;

constexpr long KVV = 5570560;   // ushorts per view: 680 tb * 8 h * 2 * 512

// ws offsets in floats
constexpr long O_KH    = 0;                        // [2] K' frag-linear hi
constexpr long O_KL    = O_KH    + 5570560;
constexpr long O_VTH   = O_KL    + 5570560;        // [2] V' frag-linear hi
constexpr long O_VTL   = O_VTH   + 5570560;
constexpr long O_QBUF  = O_VTL   + 5570560;        // [1600][256]
constexpr long O_QKV   = O_QBUF  + 409600;         // [1600][768]
constexpr long O_QSA   = O_QKV   + 1228800;        // [1600][256]
constexpr long O_QHAT  = O_QSA   + 409600;         // (unused)
constexpr long O_QN    = O_QHAT  + 409600;         // (unused)
constexpr long O_SAO   = O_QN    + 409600;         // [1600][256]
constexpr long O_OCA   = O_SAO   + 409600;         // [2][1600][256]
constexpr long O_Q12   = O_OCA   + 819200;         // [2][1600][256]
constexpr long O_QH    = O_Q12   + 819200;         // [1632][256] ushort hi
constexpr long O_QL    = O_QH    + 208896;
constexpr long O_WTH   = O_QL    + 208896;         // [6][32][8][512] ushort (frag)
constexpr long O_WTL   = O_WTH   + 393216;
constexpr long O_WQH   = O_WTL   + 393216;         // [6][16][8][512] ushort (frag)
constexpr long O_WQL   = O_WQH   + 196608;
constexpr long O_BKV   = O_WQL   + 196608;         // [6][512]
constexpr long O_BQ    = O_BKV   + 3072;           // [6][256]
constexpr long O_PO    = O_BQ    + 1536;           // (unused)
constexpr long O_PM    = O_PO    + 409600;
constexpr long O_PL    = O_PM    + 16384;
constexpr long O_PO2   = O_PL    + 16384;          // [3072][1024] CA partials
constexpr long O_PM2   = O_PO2   + 3145728;        // [3072][32]
constexpr long O_PL2   = O_PM2   + 98304;          // [3072][32]
constexpr long O_MS    = O_PL2   + 98304;          // [16][128][128]
constexpr long O_RST   = O_MS    + 262144;         // (unused)
constexpr long O_STATS = O_RST   + 8192;           // [43520][2]
constexpr long O_XH    = O_STATS + 87040;          // [2][1360][8][512] ushort (frag)
constexpr long O_XL    = O_XH    + 5570560;
constexpr long O_SQKVH = O_XL    + 5570560;        // [6][48][8][512] ushort (frag)
constexpr long O_SQKVL = O_SQKVH + 589824;
constexpr long O_SWPH  = O_SQKVL + 589824;         // [6][16][8][512] ushort (frag)
constexpr long O_SWPL  = O_SWPH  + 196608;
constexpr long O_WPH   = O_SWPL  + 196608;         // [6][16][8][512] ushort (frag)
constexpr long O_WPL   = O_WPH   + 196608;
constexpr long WS_FLOATS = O_WPL + 196608;         // ~184 MB

DI int sel4(int4 v, int i) { return i == 0 ? v.x : (i == 1 ? v.y : (i == 2 ? v.z : v.w)); }
DI unsigned short bf_rne(float x) {
  unsigned u = __float_as_uint(x);
  u += 0x7fffu + ((u >> 16) & 1u);
  return (unsigned short)(u >> 16);
}
DI float bf2f(unsigned short h) { return __uint_as_float(((unsigned)h) << 16); }
DI long frag_off(int nblk_base, int k, int n) {
  return ((long)(nblk_base + (n >> 4)) * 8 + (k >> 5)) * 512 +
         ((((k & 31) >> 3)) * 16 + (n & 15)) * 8 + (k & 7);
}

// --- fold LN into KV weights + ca_wq -> FRAGMENT-ORDER split-bf16 -----------
__global__ void fold_w2_kernel(const float* __restrict__ ng, const float* __restrict__ wk,
                               const float* __restrict__ wv, const float* __restrict__ wq,
                               unsigned short* __restrict__ WTh, unsigned short* __restrict__ WTl,
                               unsigned short* __restrict__ WQh, unsigned short* __restrict__ WQl) {
  long idx = (long)blockIdx.x * 256 + threadIdx.x;
  const long T1 = 6L * 512 * 256;
  if (idx < T1) {
    int d = idx / (512 * 256); int r = idx % (512 * 256); int n = r / 256; int k = r % 256;
    float g = ng[d * 256 + k];
    float w = (n < 256) ? wk[((long)(d * 256 + k)) * 256 + n]
                        : wv[((long)(d * 256 + k)) * 256 + (n - 256)];
    w *= g;
    unsigned short hi = bf_rne(w);
    long off = frag_off(d * 32, k, n);
    WTh[off] = hi;
    WTl[off] = bf_rne(w - bf2f(hi));
  } else {
    long j = idx - T1;
    if (j < 6L * 256 * 256) {
      int d = j / 65536; int r = j % 65536; int k = r / 256; int n = r % 256;
      float w = ng[d * 256 + k] * wq[((long)(d * 256 + k)) * 256 + n];
      unsigned short hi = bf_rne(w);
      long off = frag_off(d * 16, k, n);
      WQh[off] = hi;
      WQl[off] = bf_rne(w - bf2f(hi));
    }
  }
}

// --- split sa_wqkv / sa_wp / ca_wp into fragment-order split-bf16 -----------
__global__ void split_wall_kernel(const float* __restrict__ swqkv,
                                  const float* __restrict__ swp,
                                  const float* __restrict__ wp,
                                  unsigned short* __restrict__ SQh, unsigned short* __restrict__ SQl,
                                  unsigned short* __restrict__ SPh, unsigned short* __restrict__ SPl,
                                  unsigned short* __restrict__ WPh, unsigned short* __restrict__ WPl) {
  long idx = (long)blockIdx.x * 256 + threadIdx.x;
  const long T1 = 6L * 256 * 768;
  const long T2 = T1 + 6L * 256 * 256;
  const long T3 = T2 + 6L * 256 * 256;
  if (idx < T1) {
    int d = idx / 196608; int r = idx % 196608; int k = r / 768; int n = r % 768;
    float w = swqkv[idx];
    unsigned short hi = bf_rne(w);
    long off = frag_off(d * 48, k, n);
    SQh[off] = hi;
    SQl[off] = bf_rne(w - bf2f(hi));
  } else if (idx < T2) {
    long j = idx - T1;
    int d = j / 65536; int r = j % 65536; int k = r / 256; int n = r % 256;
    float w = swp[j];
    unsigned short hi = bf_rne(w);
    long off = frag_off(d * 16, k, n);
    SPh[off] = hi;
    SPl[off] = bf_rne(w - bf2f(hi));
  } else if (idx < T3) {
    long j = idx - T2;
    int d = j / 65536; int r = j % 65536; int k = r / 256; int n = r % 256;
    float w = wp[j];
    unsigned short hi = bf_rne(w);
    long off = frag_off(d * 16, k, n);
    WPh[off] = hi;
    WPl[off] = bf_rne(w - bf2f(hi));
  }
}

__global__ void fold_b_kernel(const float* __restrict__ nb, const float* __restrict__ wk,
                              const float* __restrict__ wv, const float* __restrict__ wq,
                              float* __restrict__ bkvo, float* __restrict__ bqo) {
  int idx = blockIdx.x * 256 + threadIdx.x;
  if (idx >= 6 * 768) return;
  int d = idx / 768, j = idx % 768;
  float s = 0.f;
  if (j < 256) {
    for (int c = 0; c < 256; ++c) s = fmaf(nb[d * 256 + c], wk[(d * 256 + c) * 256 + j], s);
    bkvo[d * 512 + j] = s;
  } else if (j < 512) {
    int n = j - 256;
    for (int c = 0; c < 256; ++c) s = fmaf(nb[d * 256 + c], wv[(d * 256 + c) * 256 + n], s);
    bkvo[d * 512 + j] = s;
  } else {
    int n = j - 512;
    for (int c = 0; c < 256; ++c) s = fmaf(nb[d * 256 + c], wq[(d * 256 + c) * 256 + n], s);
    bqo[d * 256 + n] = s;
  }
}

// --- zero the Q pad rows (1600..1631) once ----------------------------------
__global__ void zero_qpad_kernel(unsigned short* __restrict__ Qh,
                                 unsigned short* __restrict__ Ql) {
  int idx = blockIdx.x * 256 + threadIdx.x;
  if (idx < 32 * 256) {
    Qh[1600 * 256 + idx] = 0;
    Ql[1600 * 256 + idx] = 0;
  }
}

// --- per-token LN statistics of feature maps ------------------------------
__global__ __launch_bounds__(256) void ln_stats_kernel(const float* __restrict__ feat,
                                                       float* __restrict__ stats,
                                                       int rowBase, int HW) {
  __shared__ float sred[4][64];
  __shared__ float qred[4][64];
  int b = blockIdx.y, t0 = blockIdx.x * 64;
  int tx = threadIdx.x & 63, ty = threadIdx.x >> 6;
  const float* fb = feat + (long)b * 256 * HW;
  float s = 0.f, q = 0.f;
  for (int k = 0; k < 64; ++k) {
    int c = ty * 64 + k;
    float v = fb[(long)c * HW + t0 + tx];
    s += v; q += v * v;
  }
  sred[ty][tx] = s; qred[ty][tx] = q;
  __syncthreads();
  if (ty == 0) {
    float ts = sred[0][tx] + sred[1][tx] + sred[2][tx] + sred[3][tx];
    float tq = qred[0][tx] + qred[1][tx] + qred[2][tx] + qred[3][tx];
    float m = ts * (1.f / 256.f);
    float var = tq * (1.f / 256.f) - m * m;
    int row = rowBase + b * HW + t0 + tx;
    stats[row * 2 + 0] = m;
    stats[row * 2 + 1] = rsqrtf(var + 1e-5f);
  }
}

// --- build LN-normalized split-bf16 X in FRAGMENT ORDER ---------------------
__global__ __launch_bounds__(256) void ln_split_x_kernel(
    const float* __restrict__ f0, const float* __restrict__ f1,
    const float* __restrict__ f2, const float* __restrict__ f3,
    const float* __restrict__ stats, int vbase,
    unsigned short* __restrict__ Xh, unsigned short* __restrict__ Xl) {
  __shared__ unsigned short Th[64][66], Tl[64][66];
  int m0 = blockIdx.x * 64;
  const float* fp; int HW, rel;
  if (m0 < 16384)      { fp = f0; HW = 4096; rel = m0; }
  else if (m0 < 20480) { fp = f1; HW = 1024; rel = m0 - 16384; }
  else if (m0 < 21504) { fp = f2; HW = 256;  rel = m0 - 20480; }
  else                 { fp = f3; HW = 64;   rel = m0 - 21504; }
  int b = rel / HW, t0 = rel % HW;
  const float* fb = fp + (long)b * 256 * HW + t0;
  int t = threadIdx.x & 63, cg4 = threadIdx.x >> 6;
  float mean = stats[(vbase + m0 + t) * 2 + 0];
  float rstd = stats[(vbase + m0 + t) * 2 + 1];
  long mtb = (long)((vbase + m0) >> 4);
  int lmt = threadIdx.x >> 6, lane = threadIdx.x & 63;
  int fr = lane & 15, g = lane >> 4;
  for (int cgo = 0; cgo < 4; ++cgo) {
    if (cgo) __syncthreads();
#pragma unroll
    for (int i = 0; i < 16; ++i) {
      int c = cgo * 64 + cg4 * 16 + i;
      float x = (fb[(long)c * HW + t] - mean) * rstd;
      unsigned short hi = bf_rne(x);
      Th[t][cg4 * 16 + i] = hi;
      Tl[t][cg4 * 16 + i] = bf_rne(x - bf2f(hi));
    }
    __syncthreads();
#pragma unroll
    for (int sk = 0; sk < 2; ++sk) {
      u16x8 vh = *(const u16x8*)&Th[lmt * 16 + fr][sk * 32 + 8 * g];
      u16x8 vl = *(const u16x8*)&Tl[lmt * 16 + fr][sk * 32 + 8 * g];
      long dst = ((mtb + lmt) * 8 + cgo * 2 + sk) * 512 + lane * 8;
      *(u16x8*)&Xh[dst] = vh;
      *(u16x8*)&Xl[dst] = vl;
    }
  }
}

__global__ void init_q_kernel(const float* __restrict__ qe, float* __restrict__ qb) {
  int idx = blockIdx.x * 256 + threadIdx.x;
  if (idx < 1600 * 256) {
    int row = idx >> 8, c = idx & 255;
    qb[idx] = qe[(row % 100) * 256 + c];
  }
}

// --- generic MFMA projection: C[M,N] = A[M,256] @ W + bias (fp32 out) -------
__global__ __launch_bounds__(256) void gemm_mfma_kernel(
    const float* __restrict__ A,
    const unsigned short* __restrict__ Wh, const unsigned short* __restrict__ Wl,
    const float* __restrict__ bias, float* __restrict__ C, int N) {
  __shared__ unsigned short Ah[2][8][512], Al[2][8][512];
  int n0 = blockIdx.x * 128;
  int m0 = blockIdx.y * 32;
  int tid = threadIdx.x;
  int w = tid >> 6, lane = tid & 63;
  int fr = lane & 15, g = lane >> 4;
#pragma unroll
  for (int mt = 0; mt < 2; ++mt)
#pragma unroll
    for (int kk = 0; kk < 2; ++kk) {
      int ks = 2 * w + kk;
      const float* src = &A[(long)(m0 + mt * 16 + fr) * 256 + ks * 32 + 8 * g];
      float4 f0 = *(const float4*)src;
      float4 f1 = *(const float4*)(src + 4);
      float vals[8] = {f0.x, f0.y, f0.z, f0.w, f1.x, f1.y, f1.z, f1.w};
      union { u16x8 v; unsigned short us[8]; } hh, ll;
#pragma unroll
      for (int e = 0; e < 8; ++e) {
        unsigned short hi = bf_rne(vals[e]);
        hh.us[e] = hi;
        ll.us[e] = bf_rne(vals[e] - bf2f(hi));
      }
      *(u16x8*)&Ah[mt][ks][lane * 8] = hh.v;
      *(u16x8*)&Al[mt][ks][lane * 8] = ll.v;
    }
  __syncthreads();
  f32x4 acc[2][2];
#pragma unroll
  for (int c4 = 0; c4 < 2; ++c4)
#pragma unroll
    for (int mt = 0; mt < 2; ++mt)
#pragma unroll
      for (int r = 0; r < 4; ++r) acc[c4][mt][r] = 0.f;
  for (int ks = 0; ks < 8; ++ks) {
    bf16x8 ah[2], al[2], wh[2], wl[2];
#pragma unroll
    for (int mt = 0; mt < 2; ++mt) {
      ah[mt] = *(const bf16x8*)&Ah[mt][ks][lane * 8];
      al[mt] = *(const bf16x8*)&Al[mt][ks][lane * 8];
    }
#pragma unroll
    for (int c4 = 0; c4 < 2; ++c4) {
      long wb = ((long)((n0 >> 4) + w * 2 + c4) * 8 + ks) * 512 + lane * 8;
      wh[c4] = *(const bf16x8*)&Wh[wb];
      wl[c4] = *(const bf16x8*)&Wl[wb];
    }
#pragma unroll
    for (int c4 = 0; c4 < 2; ++c4)
#pragma unroll
      for (int mt = 0; mt < 2; ++mt) {
        acc[c4][mt] = MFMA16(wh[c4], ah[mt], acc[c4][mt]);
        acc[c4][mt] = MFMA16(wh[c4], al[mt], acc[c4][mt]);
        acc[c4][mt] = MFMA16(wl[c4], ah[mt], acc[c4][mt]);
      }
  }
#pragma unroll
  for (int c4 = 0; c4 < 2; ++c4) {
    int nb = n0 + w * 32 + c4 * 16 + 4 * g;
    float4 bv = make_float4(0.f, 0.f, 0.f, 0.f);
    if (bias) bv = *(const float4*)&bias[nb];
#pragma unroll
    for (int mt = 0; mt < 2; ++mt) {
      int token = m0 + mt * 16 + fr;
      float4 o;
      o.x = acc[c4][mt][0] + bv.x;
      o.y = acc[c4][mt][1] + bv.y;
      o.z = acc[c4][mt][2] + bv.z;
      o.w = acc[c4][mt][3] + bv.w;
      *(float4*)&C[(long)token * N + nb] = o;
    }
  }
}

// --- Q-projection MFMA with INLINE row-LN; emits scaled split-bf16 Qh/Ql ----
__global__ __launch_bounds__(256) void gemm_mfma_qln_kernel(
    const float* __restrict__ A,
    const unsigned short* __restrict__ Wh, const unsigned short* __restrict__ Wl,
    const float* __restrict__ bias,
    unsigned short* __restrict__ Qh, unsigned short* __restrict__ Ql) {
  __shared__ unsigned short Ah[2][8][512], Al[2][8][512];
  __shared__ float part[32][16][2];
  __shared__ float stats[32][2];
  int n0 = blockIdx.x * 128;
  int m0 = blockIdx.y * 32;
  int tid = threadIdx.x;
  int w = tid >> 6, lane = tid & 63;
  int fr = lane & 15, g = lane >> 4;
  const float SC = 0.17677669529663689f;
  float vals[2][16];
#pragma unroll
  for (int mt = 0; mt < 2; ++mt) {
    float s = 0.f, q = 0.f;
#pragma unroll
    for (int kk = 0; kk < 2; ++kk) {
      int ks = 2 * w + kk;
      const float* src = &A[(long)(m0 + mt * 16 + fr) * 256 + ks * 32 + 8 * g];
      float4 f0 = *(const float4*)src;
      float4 f1 = *(const float4*)(src + 4);
      vals[mt][kk * 8 + 0] = f0.x; vals[mt][kk * 8 + 1] = f0.y;
      vals[mt][kk * 8 + 2] = f0.z; vals[mt][kk * 8 + 3] = f0.w;
      vals[mt][kk * 8 + 4] = f1.x; vals[mt][kk * 8 + 5] = f1.y;
      vals[mt][kk * 8 + 6] = f1.z; vals[mt][kk * 8 + 7] = f1.w;
#pragma unroll
      for (int e = 0; e < 8; ++e) {
        float x = vals[mt][kk * 8 + e];
        s += x; q += x * x;
      }
    }
    part[mt * 16 + fr][w * 4 + g][0] = s;
    part[mt * 16 + fr][w * 4 + g][1] = q;
  }
  __syncthreads();
  if (tid < 32) {
    float s = 0.f, q = 0.f;
#pragma unroll
    for (int j = 0; j < 16; ++j) { s += part[tid][j][0]; q += part[tid][j][1]; }
    float mn = s * (1.f / 256.f);
    float var = q * (1.f / 256.f) - mn * mn;
    stats[tid][0] = mn;
    stats[tid][1] = rsqrtf(var + 1e-5f);
  }
  __syncthreads();
#pragma unroll
  for (int mt = 0; mt < 2; ++mt) {
    float mean = stats[mt * 16 + fr][0], rstd = stats[mt * 16 + fr][1];
#pragma unroll
    for (int kk = 0; kk < 2; ++kk) {
      int ks = 2 * w + kk;
      union { u16x8 v; unsigned short us[8]; } hh, ll;
#pragma unroll
      for (int e = 0; e < 8; ++e) {
        float x = (vals[mt][kk * 8 + e] - mean) * rstd;
        unsigned short hi = bf_rne(x);
        hh.us[e] = hi;
        ll.us[e] = bf_rne(x - bf2f(hi));
      }
      *(u16x8*)&Ah[mt][ks][lane * 8] = hh.v;
      *(u16x8*)&Al[mt][ks][lane * 8] = ll.v;
    }
  }
  __syncthreads();
  f32x4 acc[2][2];
#pragma unroll
  for (int c4 = 0; c4 < 2; ++c4)
#pragma unroll
    for (int mt = 0; mt < 2; ++mt)
#pragma unroll
      for (int r = 0; r < 4; ++r) acc[c4][mt][r] = 0.f;
  for (int ks = 0; ks < 8; ++ks) {
    bf16x8 ah[2], al[2], wh[2], wl[2];
#pragma unroll
    for (int mt = 0; mt < 2; ++mt) {
      ah[mt] = *(const bf16x8*)&Ah[mt][ks][lane * 8];
      al[mt] = *(const bf16x8*)&Al[mt][ks][lane * 8];
    }
#pragma unroll
    for (int c4 = 0; c4 < 2; ++c4) {
      long wb = ((long)((n0 >> 4) + w * 2 + c4) * 8 + ks) * 512 + lane * 8;
      wh[c4] = *(const bf16x8*)&Wh[wb];
      wl[c4] = *(const bf16x8*)&Wl[wb];
    }
#pragma unroll
    for (int c4 = 0; c4 < 2; ++c4)
#pragma unroll
      for (int mt = 0; mt < 2; ++mt) {
        acc[c4][mt] = MFMA16(wh[c4], ah[mt], acc[c4][mt]);
        acc[c4][mt] = MFMA16(wh[c4], al[mt], acc[c4][mt]);
        acc[c4][mt] = MFMA16(wl[c4], ah[mt], acc[c4][mt]);
      }
  }
#pragma unroll
  for (int c4 = 0; c4 < 2; ++c4) {
    int nb = n0 + w * 32 + c4 * 16 + 4 * g;
    float4 bv = *(const float4*)&bias[nb];
    float bvs[4] = {bv.x, bv.y, bv.z, bv.w};
#pragma unroll
    for (int mt = 0; mt < 2; ++mt) {
      int token = m0 + mt * 16 + fr;
      ushort4 uh, ul;
#pragma unroll
      for (int r = 0; r < 4; ++r) {
        float val = (acc[c4][mt][r] + bvs[r]) * SC;
        unsigned short hi = bf_rne(val);
        ((unsigned short*)&uh)[r] = hi;
        ((unsigned short*)&ul)[r] = bf_rne(val - bf2f(hi));
      }
      *(ushort4*)&Qh[(long)token * 256 + nb] = uh;
      *(ushort4*)&Ql[(long)token * 256 + nb] = ul;
    }
  }
}

// --- KV projection v9: 32-token tiles, grid 2720, XCD-pair swizzle ----------
__global__ __launch_bounds__(256) void gemm_kv8_kernel(
    const unsigned short* __restrict__ Xh, const unsigned short* __restrict__ Xl,
    const unsigned short* __restrict__ Wh, const unsigned short* __restrict__ Wl,
    const float* __restrict__ bias,
    unsigned short* __restrict__ Kh, unsigned short* __restrict__ Kl,
    unsigned short* __restrict__ VTh, unsigned short* __restrict__ VTl) {
  __shared__ unsigned short Tls[10240];   // K: [32][264]=8448, V: [256][40]=10240
  int bid = blockIdx.x;
  int nh = (bid >> 3) & 1;
  int t = (bid & 7) | ((bid >> 4) << 3);   // 0..1359
  int v = t / 680;
  int mi = t - v * 680;                    // 32-token tile index 0..679
  int tid = threadIdx.x;
  int w = tid >> 6, lane = tid & 63;
  int fr = lane & 15, g = lane >> 4;
  long xmtb = (long)(v * 1360 + mi * 2);
  f32x4 acc[4][2];
#pragma unroll
  for (int c4 = 0; c4 < 4; ++c4)
#pragma unroll
    for (int mt = 0; mt < 2; ++mt)
#pragma unroll
      for (int r = 0; r < 4; ++r) acc[c4][mt][r] = 0.f;
  for (int ks = 0; ks < 8; ++ks) {
    bf16x8 xh_[2], xl_[2], wh_[4], wl_[4];
#pragma unroll
    for (int mt = 0; mt < 2; ++mt) {
      long ar = ((xmtb + mt) * 8 + ks) * 512 + lane * 8;
      xh_[mt] = *(const bf16x8*)&Xh[ar];
      xl_[mt] = *(const bf16x8*)&Xl[ar];
    }
#pragma unroll
    for (int c4 = 0; c4 < 4; ++c4) {
      long br = ((long)(nh * 16 + c4 * 4 + w) * 8 + ks) * 512 + lane * 8;
      wh_[c4] = *(const bf16x8*)&Wh[br];
      wl_[c4] = *(const bf16x8*)&Wl[br];
    }
    if (nh == 0) {
#pragma unroll
      for (int c4 = 0; c4 < 4; ++c4)
#pragma unroll
        for (int mt = 0; mt < 2; ++mt) {
          acc[c4][mt] = MFMA16(wh_[c4], xh_[mt], acc[c4][mt]);
          acc[c4][mt] = MFMA16(wh_[c4], xl_[mt], acc[c4][mt]);
          acc[c4][mt] = MFMA16(wl_[c4], xh_[mt], acc[c4][mt]);
        }
    } else {
#pragma unroll
      for (int c4 = 0; c4 < 4; ++c4)
#pragma unroll
        for (int mt = 0; mt < 2; ++mt) {
          acc[c4][mt] = MFMA16(xh_[mt], wh_[c4], acc[c4][mt]);
          acc[c4][mt] = MFMA16(xl_[mt], wh_[c4], acc[c4][mt]);
          acc[c4][mt] = MFMA16(xh_[mt], wl_[c4], acc[c4][mt]);
        }
    }
  }
  long kvoff = (long)v * KVV;
  long tbb = (long)mi;
  if (nh == 0) {
    // K: D[row=n 4g+r][col=token fr]; LDS [32 tok][264] then K' frag write.
    for (int part = 0; part < 2; ++part) {
      __syncthreads();
#pragma unroll
      for (int c4 = 0; c4 < 4; ++c4) {
        int nb = c4 * 64 + w * 16 + 4 * g;
        float4 bv4 = *(const float4*)&bias[nb];
        float bvs[4] = {bv4.x, bv4.y, bv4.z, bv4.w};
#pragma unroll
        for (int mt = 0; mt < 2; ++mt) {
          int tok = mt * 16 + fr;
          ushort4 u;
#pragma unroll
          for (int r = 0; r < 4; ++r) {
            float val = acc[c4][mt][r] + bvs[r];
            unsigned short hi = bf_rne(val);
            ((unsigned short*)&u)[r] = (part == 0) ? hi : bf_rne(val - bf2f(hi));
          }
          *(ushort4*)&Tls[tok * 264 + nb] = u;
        }
      }
      __syncthreads();
      unsigned short* dst = (part == 0) ? Kh : Kl;
#pragma unroll
      for (int i = 0; i < 4; ++i) {
        int gid = tid + 256 * i;        // 0..1023
        int lane2 = gid & 63;
        int rest = gid >> 6;            // h2*2 + t16, 0..15
        int t16 = rest & 1;
        int h2 = (rest >> 1) & 7;
        int fr2 = lane2 & 15, g2 = lane2 >> 4;
        int row = 8 * (fr2 >> 2) + (fr2 & 3) + 4 * t16;   // kperm, 0..31
        u16x8 val = *(const u16x8*)&Tls[row * 264 + h2 * 32 + 8 * g2];
        long off = kvoff + ((tbb * 8 + h2) * 2 + t16) * 512 + lane2 * 8;
        *(u16x8*)&dst[off] = val;
      }
    }
  } else {
    // V: D[row=token 4g+r][col=nv fr]; LDS [256 nv][40] then V' frag write.
    for (int part = 0; part < 2; ++part) {
      __syncthreads();
#pragma unroll
      for (int c4 = 0; c4 < 4; ++c4) {
        int nv = c4 * 64 + w * 16 + fr;
        float bv = bias[256 + nv];
#pragma unroll
        for (int mt = 0; mt < 2; ++mt) {
          int tok = mt * 16 + 4 * g;
          ushort4 u;
#pragma unroll
          for (int r = 0; r < 4; ++r) {
            float val = acc[c4][mt][r] + bv;
            unsigned short hi = bf_rne(val);
            ((unsigned short*)&u)[r] = (part == 0) ? hi : bf_rne(val - bf2f(hi));
          }
          *(ushort4*)&Tls[nv * 40 + tok] = u;
        }
      }
      __syncthreads();
      unsigned short* dst = (part == 0) ? VTh : VTl;
#pragma unroll
      for (int i = 0; i < 4; ++i) {
        int gid = tid + 256 * i;
        int lane2 = gid & 63;
        int rest = gid >> 6;            // h2*2 + d16, 0..15
        int d16 = rest & 1;
        int h2 = (rest >> 1) & 7;
        int fr2 = lane2 & 15, g2 = lane2 >> 4;
        int row = h2 * 32 + d16 * 16 + fr2;   // nv
        int col = 8 * g2;                     // local token
        u16x8 val = *(const u16x8*)&Tls[row * 40 + col];
        long off = kvoff + ((tbb * 8 + h2) * 2 + d16) * 512 + lane2 * 8;
        *(u16x8*)&dst[off] = val;
      }
    }
  }
}

// --- SA flash (VALU path); nc==1 so writes normalized output directly -------
__global__ __launch_bounds__(256) void flash_kernel(const float* __restrict__ qp, int qld,
                                                    const float* __restrict__ kb,
                                                    const float* __restrict__ vb, int kvld,
                                                    int4 startv, int4 nchv, int4 nkv,
                                                    int4 koffv, int4 kstrbv,
                                                    float* __restrict__ outp, int outld) {
  __shared__ float Kt[32][36];
  __shared__ float Vt[32][36];
  int bid = blockIdx.x;
  int s1 = startv.y, s2 = startv.z, s3 = startv.w;
  int l = (bid < s1) ? 0 : (bid < s2) ? 1 : (bid < s3) ? 2 : 3;
  int r = bid - sel4(startv, l);
  int nc = sel4(nchv, l);
  int b = r / (8 * nc);
  int h = (r / nc) & 7;
  int ch = r % nc;
  int Nk = sel4(nkv, l);
  int qr0 = (l * 4 + b) * 100;
  int kr0 = sel4(koffv, l) + b * sel4(kstrbv, l);
  int j0 = ch * 128;
  int jn = min(128, Nk - j0);
  int tiles = (jn + 31) >> 5;
  int tid = threadIdx.x;
  int qi = tid >> 1, half = tid & 1, ho = half * 16, jb = half * 16;
  const float SC = 0.17677669529663689f;
  float4 q8[8];
  if (qi < 100) {
    const float* qrow = qp + (long)(qr0 + qi) * qld + h * 32;
#pragma unroll
    for (int k = 0; k < 8; ++k) {
      float4 f = *(const float4*)&qrow[4 * k];
      q8[k] = make_float4(f.x * SC, f.y * SC, f.z * SC, f.w * SC);
    }
  } else {
#pragma unroll
    for (int k = 0; k < 8; ++k) q8[k] = make_float4(0.f, 0.f, 0.f, 0.f);
  }
  float m = -1e30f, lsum = 0.f;
  float o[16];
#pragma unroll
  for (int i = 0; i < 16; ++i) o[i] = 0.f;

  for (int kt = 0; kt < tiles; ++kt) {
    __syncthreads();
    {
      int rr = tid >> 3, c4 = (tid & 7) * 4;
      int jr = kt * 32 + rr;
      float4 kf = make_float4(0.f, 0.f, 0.f, 0.f), vf = kf;
      if (jr < jn) {
        long g = (long)(kr0 + j0 + jr) * kvld + h * 32 + c4;
        kf = *(const float4*)&kb[g];
        vf = *(const float4*)&vb[g];
      }
      *(float4*)&Kt[rr][c4 ^ (rr & 16)] = kf;
      *(float4*)&Vt[rr][c4] = vf;
    }
    __syncthreads();
    float sv[16];
#pragma unroll
    for (int j = 0; j < 16; ++j) {
      float s = 0.f;
#pragma unroll
      for (int k4 = 0; k4 < 8; ++k4) {
        float4 kv = *(const float4*)&Kt[jb + j][(4 * k4) ^ jb];
        s = fmaf(q8[k4].x, kv.x, s); s = fmaf(q8[k4].y, kv.y, s);
        s = fmaf(q8[k4].z, kv.z, s); s = fmaf(q8[k4].w, kv.w, s);
      }
      int jglob = j0 + kt * 32 + jb + j;
      sv[j] = (jglob < Nk) ? s : -1e30f;
    }
    float tmax = sv[0];
#pragma unroll
    for (int j = 1; j < 16; ++j) tmax = fmaxf(tmax, sv[j]);
    tmax = fmaxf(tmax, __shfl_xor(tmax, 1));
    float mnew = fmaxf(m, tmax);
    float scale = __expf(m - mnew);
    float p[16]; float psum = 0.f;
#pragma unroll
    for (int j = 0; j < 16; ++j) {
      int jglob = j0 + kt * 32 + jb + j;
      float e = (jglob < Nk) ? __expf(sv[j] - mnew) : 0.f;
      p[j] = e; psum += e;
    }
    psum += __shfl_xor(psum, 1);
    lsum = lsum * scale + psum;
    m = mnew;
#pragma unroll
    for (int i = 0; i < 16; ++i) o[i] *= scale;
    float pO[16];
#pragma unroll
    for (int j = 0; j < 16; ++j) pO[j] = __shfl_xor(p[j], 1);
    int jbO = jb ^ 16;
#pragma unroll
    for (int j = 0; j < 16; ++j) {
      float pj = p[j];
      const float* vrow = &Vt[jb + j][ho];
#pragma unroll
      for (int k = 0; k < 4; ++k) {
        float4 v4 = *(const float4*)&vrow[4 * k];
        o[4 * k + 0] = fmaf(pj, v4.x, o[4 * k + 0]);
        o[4 * k + 1] = fmaf(pj, v4.y, o[4 * k + 1]);
        o[4 * k + 2] = fmaf(pj, v4.z, o[4 * k + 2]);
        o[4 * k + 3] = fmaf(pj, v4.w, o[4 * k + 3]);
      }
    }
#pragma unroll
    for (int j = 0; j < 16; ++j) {
      float pj = pO[j];
      const float* vrow = &Vt[jbO + j][ho];
#pragma unroll
      for (int k = 0; k < 4; ++k) {
        float4 v4 = *(const float4*)&vrow[4 * k];
        o[4 * k + 0] = fmaf(pj, v4.x, o[4 * k + 0]);
        o[4 * k + 1] = fmaf(pj, v4.y, o[4 * k + 1]);
        o[4 * k + 2] = fmaf(pj, v4.z, o[4 * k + 2]);
        o[4 * k + 3] = fmaf(pj, v4.w, o[4 * k + 3]);
      }
    }
  }
  if (qi < 100) {
    float inv = 1.f / lsum;
    float* orow = outp + (long)(qr0 + qi) * outld + h * 32 + ho;
#pragma unroll
    for (int k = 0; k < 4; ++k)
      *(float4*)&orow[4 * k] = make_float4(o[4 * k] * inv, o[4 * k + 1] * inv,
                                           o[4 * k + 2] * inv, o[4 * k + 3] * inv);
  }
}

// --- CA flash v3: fully coalesced K'/V' fragment loads ----------------------
__global__ __launch_bounds__(256) void flash_ca2_kernel(
    const unsigned short* __restrict__ Qh, const unsigned short* __restrict__ Ql,
    const unsigned short* __restrict__ Kh, const unsigned short* __restrict__ Kl,
    const unsigned short* __restrict__ VTh, const unsigned short* __restrict__ VTl,
    float* __restrict__ po, float* __restrict__ pm, float* __restrict__ pl) {
  int tid = threadIdx.x;
  int uu = blockIdx.x * 4 + (tid >> 6);
  int v = uu / 1536;
  int u = uu - v * 1536;
  int lane = tid & 63;
  int fr = lane & 15, g = lane >> 4;
  int base, lognc, koff, kstr, ntile, l;
  if (u < 1024)      { base = 0;    lognc = 3; koff = 0;     kstr = 4096; ntile = 16; l = 0; }
  else if (u < 1280) { base = 1024; lognc = 1; koff = 16384; kstr = 1024; ntile = 16; l = 1; }
  else if (u < 1408) { base = 1280; lognc = 0; koff = 20480; kstr = 256;  ntile = 8;  l = 2; }
  else               { base = 1408; lognc = 0; koff = 21504; kstr = 64;   ntile = 2;  l = 3; }
  int r = u - base;
  int qg = r & 3; r >>= 2;
  int ch = r & ((1 << lognc) - 1); r >>= lognc;
  int h = r & 7, b = r >> 3;
  long kvoff = (long)v * KVV;
  long qoff = ((long)((l * 4 + b) * 100 + qg * 32)) * 256 + h * 32 + 8 * g;
  bf16x8 qh0 = *(const bf16x8*)&Qh[qoff + fr * 256];
  bf16x8 qh1 = *(const bf16x8*)&Qh[qoff + (16 + fr) * 256];
  bf16x8 ql0 = *(const bf16x8*)&Ql[qoff + fr * 256];
  bf16x8 ql1 = *(const bf16x8*)&Ql[qoff + (16 + fr) * 256];
  int tb0 = (koff + b * kstr + ch * 512) >> 5;
  f32x4 o00 = {0.f, 0.f, 0.f, 0.f}, o01 = o00, o10 = o00, o11 = o00;
  float m0r = -1e30f, m1r = -1e30f, l0r = 0.f, l1r = 0.f;

  for (int kt = 0; kt < ntile; ++kt) {
    long fb = kvoff + (((long)(tb0 + kt) * 8 + h) * 2) * 512 + lane * 8;
    bf16x8 kh0 = *(const bf16x8*)&Kh[fb];
    bf16x8 kl0 = *(const bf16x8*)&Kl[fb];
    bf16x8 kh1 = *(const bf16x8*)&Kh[fb + 512];
    bf16x8 kl1 = *(const bf16x8*)&Kl[fb + 512];
    bf16x8 vh0 = *(const bf16x8*)&VTh[fb];
    bf16x8 vl0 = *(const bf16x8*)&VTl[fb];
    bf16x8 vh1 = *(const bf16x8*)&VTh[fb + 512];
    bf16x8 vl1 = *(const bf16x8*)&VTl[fb + 512];
    f32x4 zz = {0.f, 0.f, 0.f, 0.f};
    f32x4 s00 = zz, s01 = zz, s10 = zz, s11 = zz;
    s00 = MFMA16(kh0, qh0, s00); s00 = MFMA16(kl0, qh0, s00); s00 = MFMA16(kh0, ql0, s00);
    s01 = MFMA16(kh1, qh0, s01); s01 = MFMA16(kl1, qh0, s01); s01 = MFMA16(kh1, ql0, s01);
    s10 = MFMA16(kh0, qh1, s10); s10 = MFMA16(kl0, qh1, s10); s10 = MFMA16(kh0, ql1, s10);
    s11 = MFMA16(kh1, qh1, s11); s11 = MFMA16(kl1, qh1, s11); s11 = MFMA16(kh1, ql1, s11);
    {
      float t0 = fmaxf(fmaxf(s00[0], s00[1]), fmaxf(s00[2], s00[3]));
      float t1 = fmaxf(fmaxf(s01[0], s01[1]), fmaxf(s01[2], s01[3]));
      float tm = fmaxf(t0, t1);
      tm = fmaxf(tm, __shfl_xor(tm, 16));
      tm = fmaxf(tm, __shfl_xor(tm, 32));
      float mn = fmaxf(m0r, tm);
      float sc = __expf(m0r - mn); m0r = mn;
      float p[8]; float ps = 0.f;
#pragma unroll
      for (int i = 0; i < 4; ++i) { p[i] = __expf(s00[i] - mn); ps += p[i]; }
#pragma unroll
      for (int i = 0; i < 4; ++i) { p[4 + i] = __expf(s01[i] - mn); ps += p[4 + i]; }
      l0r = l0r * sc + ps;
      union { bf16x8 v; unsigned short us[8]; } ph, plo;
#pragma unroll
      for (int e = 0; e < 8; ++e) {
        unsigned short hi = bf_rne(p[e]);
        ph.us[e] = hi;
        plo.us[e] = bf_rne(p[e] - bf2f(hi));
      }
#pragma unroll
      for (int i = 0; i < 4; ++i) { o00[i] *= sc; o01[i] *= sc; }
      o00 = MFMA16(vh0, ph.v, o00); o00 = MFMA16(vl0, ph.v, o00); o00 = MFMA16(vh0, plo.v, o00);
      o01 = MFMA16(vh1, ph.v, o01); o01 = MFMA16(vl1, ph.v, o01); o01 = MFMA16(vh1, plo.v, o01);
    }
    {
      float t0 = fmaxf(fmaxf(s10[0], s10[1]), fmaxf(s10[2], s10[3]));
      float t1 = fmaxf(fmaxf(s11[0], s11[1]), fmaxf(s11[2], s11[3]));
      float tm = fmaxf(t0, t1);
      tm = fmaxf(tm, __shfl_xor(tm, 16));
      tm = fmaxf(tm, __shfl_xor(tm, 32));
      float mn = fmaxf(m1r, tm);
      float sc = __expf(m1r - mn); m1r = mn;
      float p[8]; float ps = 0.f;
#pragma unroll
      for (int i = 0; i < 4; ++i) { p[i] = __expf(s10[i] - mn); ps += p[i]; }
#pragma unroll
      for (int i = 0; i < 4; ++i) { p[4 + i] = __expf(s11[i] - mn); ps += p[4 + i]; }
      l1r = l1r * sc + ps;
      union { bf16x8 v; unsigned short us[8]; } ph, plo;
#pragma unroll
      for (int e = 0; e < 8; ++e) {
        unsigned short hi = bf_rne(p[e]);
        ph.us[e] = hi;
        plo.us[e] = bf_rne(p[e] - bf2f(hi));
      }
#pragma unroll
      for (int i = 0; i < 4; ++i) { o10[i] *= sc; o11[i] *= sc; }
      o10 = MFMA16(vh0, ph.v, o10); o10 = MFMA16(vl0, ph.v, o10); o10 = MFMA16(vh0, plo.v, o10);
      o11 = MFMA16(vh1, ph.v, o11); o11 = MFMA16(vl1, ph.v, o11); o11 = MFMA16(vh1, plo.v, o11);
    }
  }
  l0r += __shfl_xor(l0r, 16); l0r += __shfl_xor(l0r, 32);
  l1r += __shfl_xor(l1r, 16); l1r += __shfl_xor(l1r, 32);
  long pob = (long)uu * 1024;
  *(f32x4*)&po[pob + fr * 32 + 4 * g] = o00;
  *(f32x4*)&po[pob + fr * 32 + 16 + 4 * g] = o01;
  *(f32x4*)&po[pob + (16 + fr) * 32 + 4 * g] = o10;
  *(f32x4*)&po[pob + (16 + fr) * 32 + 16 + 4 * g] = o11;
  if (g == 0) {
    pm[uu * 32 + fr] = m0r;       pl[uu * 32 + fr] = l0r;
    pm[uu * 32 + 16 + fr] = m1r;  pl[uu * 32 + 16 + fr] = l1r;
  }
}

// --- CA combine v2 (both views): unit = (v,l,b,h,qg), 1024 blocks -----------
__global__ __launch_bounds__(256) void combine2_kernel(const float* __restrict__ po,
                                                       const float* __restrict__ pm,
                                                       const float* __restrict__ pl,
                                                       float* __restrict__ oca) {
  int gu = blockIdx.x;
  int v = gu >> 9;
  int u = gu & 511;
  int l = u >> 7, ur = u & 127;
  int b = ur >> 5, h = (ur >> 2) & 7, qg = ur & 3;
  int nc, base;
  if (l == 0)      { nc = 8; base = 0; }
  else if (l == 1) { nc = 2; base = 1024; }
  else if (l == 2) { nc = 1; base = 1280; }
  else             { nc = 1; base = 1408; }
  int pu0 = v * 1536 + base + ((b * 8 + h) * nc) * 4 + qg;
  int qr0 = (l * 4 + b) * 100 + qg * 32;
  int qn = min(32, 100 - qg * 32);
  float* outp = oca + (long)v * 409600;
  for (int e = threadIdx.x; e < 1024; e += 256) {
    int qi = e >> 5, d = e & 31;
    if (qi >= qn) continue;
    float mstar = -1e30f;
    for (int c = 0; c < nc; ++c) mstar = fmaxf(mstar, pm[(pu0 + 4 * c) * 32 + qi]);
    float Lt = 0.f, val = 0.f;
    for (int c = 0; c < nc; ++c) {
      float w = __expf(pm[(pu0 + 4 * c) * 32 + qi] - mstar);
      Lt = fmaf(w, pl[(pu0 + 4 * c) * 32 + qi], Lt);
      val = fmaf(w, po[(long)(pu0 + 4 * c) * 1024 + qi * 32 + d], val);
    }
    outp[(long)(qr0 + qi) * 256 + h * 32 + d] = val / Lt;
  }
}

// --- ms = q1 @ q2^T ---------------------------------------------------------
DI float dot4(float4 a, float4 b) {
  float s = a.x * b.x;
  s = fmaf(a.y, b.y, s); s = fmaf(a.z, b.z, s); s = fmaf(a.w, b.w, s);
  return s;
}
__global__ __launch_bounds__(256) void fuse_ms_kernel(const float* __restrict__ q1,
                                                      const float* __restrict__ q2,
                                                      float* __restrict__ ms) {
  __shared__ float a[32][132];
  __shared__ float bsh[32][132];
  int lb = blockIdx.x;
  int it = blockIdx.y >> 2, jt = blockIdx.y & 3;
  int tid = threadIdx.x;
  int ti = tid & 15, tj = tid >> 4;
  float acc[2][2] = {};
  for (int chalf = 0; chalf < 2; ++chalf) {
    __syncthreads();
#pragma unroll
    for (int k = 0; k < 4; ++k) {
      int i = tid + k * 256;
      int rr = i >> 5, c4 = (i & 31) * 4;
      int row1 = it * 32 + rr, row2 = jt * 32 + rr;
      float4 fa = make_float4(0.f, 0.f, 0.f, 0.f), fb = fa;
      if (row1 < 100) fa = *(const float4*)&q1[(long)(lb * 100 + row1) * 256 + chalf * 128 + c4];
      if (row2 < 100) fb = *(const float4*)&q2[(long)(lb * 100 + row2) * 256 + chalf * 128 + c4];
      *(float4*)&a[rr][c4] = fa;
      *(float4*)&bsh[rr][c4] = fb;
    }
    __syncthreads();
#pragma unroll
    for (int k4 = 0; k4 < 32; ++k4) {
      float4 a0 = *(const float4*)&a[2 * ti][4 * k4];
      float4 a1 = *(const float4*)&a[2 * ti + 1][4 * k4];
      float4 b0 = *(const float4*)&bsh[2 * tj][4 * k4];
      float4 b1 = *(const float4*)&bsh[2 * tj + 1][4 * k4];
      acc[0][0] += dot4(a0, b0); acc[0][1] += dot4(a0, b1);
      acc[1][0] += dot4(a1, b0); acc[1][1] += dot4(a1, b1);
    }
  }
#pragma unroll
  for (int i = 0; i < 2; ++i)
#pragma unroll
    for (int j = 0; j < 2; ++j)
      ms[(long)(lb * 128 + it * 32 + 2 * ti + i) * 128 + jt * 32 + 2 * tj + j] = acc[i][j];
}

// --- r1/r2 mixing + channel softmax, stats computed INLINE ------------------
__global__ __launch_bounds__(256) void fuse_apply_kernel(const float* __restrict__ ms,
                                                         const float* __restrict__ q1,
                                                         const float* __restrict__ q2,
                                                         const float* __restrict__ qsa,
                                                         float* __restrict__ qout) {
  __shared__ float pr[128], pc[128];
  __shared__ float red[8];
  __shared__ float red1[4], red2[4];
  int lb = blockIdx.x, i = blockIdx.y, tid = threadIdx.x;
  long r = lb * 100 + i;
  if (tid < 128)
    pr[tid] = (tid < 100) ? ms[(long)(lb * 128 + i) * 128 + tid] : -1e30f;
  else
    pc[tid - 128] = (tid < 228) ? ms[(long)(lb * 128 + (tid - 128)) * 128 + i] : -1e30f;
  __syncthreads();
  if (tid < 64) {
    float mx = fmaxf(pr[tid], pr[tid + 64]);
    for (int o = 32; o; o >>= 1) mx = fmaxf(mx, __shfl_xor(mx, o));
    if (tid == 0) red[0] = mx;
  } else if (tid >= 128 && tid < 192) {
    int t2 = tid - 128;
    float mx = fmaxf(pc[t2], pc[t2 + 64]);
    for (int o = 32; o; o >>= 1) mx = fmaxf(mx, __shfl_xor(mx, o));
    if (t2 == 0) red[2] = mx;
  }
  __syncthreads();
  float rm = red[0], cm = red[2];
  if (tid < 128)
    pr[tid] = (tid < 100) ? __expf(pr[tid] - rm) : 0.f;
  else
    pc[tid - 128] = (tid < 228) ? __expf(pc[tid - 128] - cm) : 0.f;
  __syncthreads();
  if (tid < 64) {
    float sm = pr[tid] + pr[tid + 64];
    for (int o = 32; o; o >>= 1) sm += __shfl_xor(sm, o);
    if (tid == 0) red[1] = sm;
  } else if (tid >= 128 && tid < 192) {
    int t2 = tid - 128;
    float sm = pc[t2] + pc[t2 + 64];
    for (int o = 32; o; o >>= 1) sm += __shfl_xor(sm, o);
    if (t2 == 0) red[3] = sm;
  }
  __syncthreads();
  float rs = red[1], cs = red[3];
  float acc1 = 0.f, acc2 = 0.f;
  for (int j = 0; j < 100; ++j) acc1 = fmaf(pr[j], q2[(long)(lb * 100 + j) * 256 + tid], acc1);
  for (int j = 0; j < 100; ++j) acc2 = fmaf(pc[j], q1[(long)(lb * 100 + j) * 256 + tid], acc2);
  acc1 /= rs;
  acc2 /= cs;
  float z = qsa[r * 256 + tid] + q1[r * 256 + tid] + acc1 + q2[r * 256 + tid] + acc2;
  float v = z;
  for (int off = 32; off; off >>= 1) v = fmaxf(v, __shfl_xor(v, off));
  int w = tid >> 6;
  if ((tid & 63) == 0) red1[w] = v;
  __syncthreads();
  float zm = fmaxf(fmaxf(red1[0], red1[1]), fmaxf(red1[2], red1[3]));
  float e = __expf(z - zm);
  float sv = e;
  for (int off = 32; off; off >>= 1) sv += __shfl_xor(sv, off);
  if ((tid & 63) == 0) red2[w] = sv;
  __syncthreads();
  float es = red2[0] + red2[1] + red2[2] + red2[3];
  qout[r * 256 + tid] = e / es;
}

// ---------------------------------------------------------------------------
extern "C" void kernel_launch(void* const* d_in, const int* in_sizes, int n_in,
                              void* d_out, int out_size, void* d_ws, size_t ws_size,
                              hipStream_t stream) {
  (void)in_sizes; (void)n_in; (void)out_size; (void)ws_size;
  const float* feats[2][4] = {
      {(const float*)d_in[0], (const float*)d_in[1], (const float*)d_in[2], (const float*)d_in[3]},
      {(const float*)d_in[4], (const float*)d_in[5], (const float*)d_in[6], (const float*)d_in[7]}};
  const float* qe   = (const float*)d_in[8];
  const float* ng   = (const float*)d_in[9];
  const float* nb   = (const float*)d_in[10];
  const float* wq   = (const float*)d_in[11];
  const float* wk   = (const float*)d_in[12];
  const float* wv   = (const float*)d_in[13];
  const float* wp   = (const float*)d_in[14];
  const float* bp   = (const float*)d_in[15];
  const float* swqkv= (const float*)d_in[16];
  const float* swp  = (const float*)d_in[17];
  const float* sbp  = (const float*)d_in[18];

  float* ws = (float*)d_ws;
  unsigned short* KHp  = (unsigned short*)(ws + O_KH);
  unsigned short* KLp  = (unsigned short*)(ws + O_KL);
  unsigned short* VTHp = (unsigned short*)(ws + O_VTH);
  unsigned short* VTLp = (unsigned short*)(ws + O_VTL);
  float* QBUFp = ws + O_QBUF;
  float* QKVp  = ws + O_QKV;
  float* QSAp  = ws + O_QSA;
  float* SAOp  = ws + O_SAO;
  float* OCAp  = ws + O_OCA;
  float* Q12p  = ws + O_Q12;
  unsigned short* QHp  = (unsigned short*)(ws + O_QH);
  unsigned short* QLp  = (unsigned short*)(ws + O_QL);
  unsigned short* WTHp = (unsigned short*)(ws + O_WTH);
  unsigned short* WTLp = (unsigned short*)(ws + O_WTL);
  unsigned short* WQHp = (unsigned short*)(ws + O_WQH);
  unsigned short* WQLp = (unsigned short*)(ws + O_WQL);
  float* BKVp  = ws + O_BKV;
  float* BQp   = ws + O_BQ;
  float* PO2p  = ws + O_PO2;
  float* PM2p  = ws + O_PM2;
  float* PL2p  = ws + O_PL2;
  float* MSp   = ws + O_MS;
  float* STATSp= ws + O_STATS;
  unsigned short* XHp  = (unsigned short*)(ws + O_XH);
  unsigned short* XLp  = (unsigned short*)(ws + O_XL);
  unsigned short* SQHp = (unsigned short*)(ws + O_SQKVH);
  unsigned short* SQLp = (unsigned short*)(ws + O_SQKVL);
  unsigned short* SPHp = (unsigned short*)(ws + O_SWPH);
  unsigned short* SPLp = (unsigned short*)(ws + O_SWPL);
  unsigned short* WPHp = (unsigned short*)(ws + O_WPH);
  unsigned short* WPLp = (unsigned short*)(ws + O_WPL);

  const int HWs[4] = {4096, 1024, 256, 64};
  const int VOs[4] = {0, 16384, 20480, 21504};

  fold_w2_kernel<<<4608, 256, 0, stream>>>(ng, wk, wv, wq, WTHp, WTLp, WQHp, WQLp);
  split_wall_kernel<<<7680, 256, 0, stream>>>(swqkv, swp, wp, SQHp, SQLp, SPHp, SPLp, WPHp, WPLp);
  fold_b_kernel<<<18, 256, 0, stream>>>(nb, wk, wv, wq, BKVp, BQp);
  zero_qpad_kernel<<<32, 256, 0, stream>>>(QHp, QLp);
  for (int v = 0; v < 2; ++v)
    for (int l = 0; l < 4; ++l)
      ln_stats_kernel<<<dim3(HWs[l] / 64, 4), 256, 0, stream>>>(
          feats[v][l], STATSp, v * 21760 + VOs[l], HWs[l]);
  for (int v = 0; v < 2; ++v)
    ln_split_x_kernel<<<340, 256, 0, stream>>>(
        feats[v][0], feats[v][1], feats[v][2], feats[v][3], STATSp, v * 21760, XHp, XLp);
  init_q_kernel<<<1600, 256, 0, stream>>>(qe, QBUFp);

  const int4 saStart = make_int4(0, 32, 64, 96);
  const int4 saNch   = make_int4(1, 1, 1, 1);
  const int4 saNk    = make_int4(100, 100, 100, 100);
  const int4 saKoff  = make_int4(0, 400, 800, 1200);
  const int4 saKstrb = make_int4(100, 100, 100, 100);

  for (int d = 0; d < 6; ++d) {
    // --- self attention (flash writes normalized output directly) ---
    gemm_mfma_kernel<<<dim3(6, 50), 256, 0, stream>>>(
        QBUFp, SQHp + (long)d * 196608, SQLp + (long)d * 196608, nullptr, QKVp, 768);
    flash_kernel<<<128, 256, 0, stream>>>(QKVp, 768, QKVp + 256, QKVp + 512, 768,
                                          saStart, saNch, saNk, saKoff, saKstrb, SAOp, 256);
    gemm_mfma_kernel<<<dim3(2, 50), 256, 0, stream>>>(
        SAOp, SPHp + (long)d * 65536, SPLp + (long)d * 65536, sbp + d * 256, QSAp, 256);
    // --- cross-attention query projection (LN + scale + split fused) ---
    gemm_mfma_qln_kernel<<<dim3(2, 50), 256, 0, stream>>>(
        QSAp, WQHp + (long)d * 65536, WQLp + (long)d * 65536, BQp + d * 256, QHp, QLp);
    // --- cross attention, both views per dispatch ---
    gemm_kv8_kernel<<<2720, 256, 0, stream>>>(
        XHp, XLp, WTHp + (long)d * 131072, WTLp + (long)d * 131072, BKVp + d * 512,
        KHp, KLp, VTHp, VTLp);
    flash_ca2_kernel<<<768, 256, 0, stream>>>(QHp, QLp, KHp, KLp, VTHp, VTLp,
                                              PO2p, PM2p, PL2p);
    combine2_kernel<<<1024, 256, 0, stream>>>(PO2p, PM2p, PL2p, OCAp);
    gemm_mfma_kernel<<<dim3(2, 100), 256, 0, stream>>>(
        OCAp, WPHp + (long)d * 65536, WPLp + (long)d * 65536, bp + d * 256, Q12p, 256);
    // --- matching fusion + channel softmax (stats inline) ---
    fuse_ms_kernel<<<dim3(16, 16), 256, 0, stream>>>(Q12p, Q12p + 409600, MSp);
    fuse_apply_kernel<<<dim3(16, 100), 256, 0, stream>>>(MSp, Q12p, Q12p + 409600,
                                                         QSAp, QBUFp);
  }
  hipMemcpyAsync(d_out, QBUFp, 409600 * sizeof(float), hipMemcpyDeviceToDevice, stream);
}

// Round 19
// 1207.705 us; speedup vs baseline: 1.0134x; 1.0134x over previous
//
#include <hip/hip_runtime.h>

// ---------------------------------------------------------------------------
// VolumeAttention: 4 feature levels x 6 decoder depths, B=4, NQ=100, C=256, H=8
// Round 19 = round 17 verbatim (best verified: 1216 us). FINAL.
// Round 18's kv8 32-token split regressed (55 us: W-traffic/output doubled,
// epilogue overhead doubled; residency-tail theory falsified) and is reverted.
//  - SA flash writes normalized output directly (nc==1 -> o/lsum).
//  - row_ln fused into Q-projection (gemm_mfma_qln).
//  - kv8: 64-token tiles, frag-linear in/out, XCD-pair swizzle.
// ---------------------------------------------------------------------------

#define DI __device__ __forceinline__
#define MFMA16(a, b, c) __builtin_amdgcn_mfma_f32_16x16x32_bf16(a, b, c, 0, 0, 0)

typedef __attribute__((ext_vector_type(8))) short bf16x8;
typedef __attribute__((ext_vector_type(8))) unsigned short u16x8;
typedef __attribute__((ext_vector_type(4))) float f32x4;

constexpr long KVV = 5570560;   // ushorts per view: 680 tb * 8 h * 2 * 512

// ws offsets in floats
constexpr long O_KH    = 0;                        // [2] K' frag-linear hi
constexpr long O_KL    = O_KH    + 5570560;
constexpr long O_VTH   = O_KL    + 5570560;        // [2] V' frag-linear hi
constexpr long O_VTL   = O_VTH   + 5570560;
constexpr long O_QBUF  = O_VTL   + 5570560;        // [1600][256]
constexpr long O_QKV   = O_QBUF  + 409600;         // [1600][768]
constexpr long O_QSA   = O_QKV   + 1228800;        // [1600][256]
constexpr long O_QHAT  = O_QSA   + 409600;         // (unused)
constexpr long O_QN    = O_QHAT  + 409600;         // (unused)
constexpr long O_SAO   = O_QN    + 409600;         // [1600][256]
constexpr long O_OCA   = O_SAO   + 409600;         // [2][1600][256]
constexpr long O_Q12   = O_OCA   + 819200;         // [2][1600][256]
constexpr long O_QH    = O_Q12   + 819200;         // [1632][256] ushort hi
constexpr long O_QL    = O_QH    + 208896;
constexpr long O_WTH   = O_QL    + 208896;         // [6][32][8][512] ushort (frag)
constexpr long O_WTL   = O_WTH   + 393216;
constexpr long O_WQH   = O_WTL   + 393216;         // [6][16][8][512] ushort (frag)
constexpr long O_WQL   = O_WQH   + 196608;
constexpr long O_BKV   = O_WQL   + 196608;         // [6][512]
constexpr long O_BQ    = O_BKV   + 3072;           // [6][256]
constexpr long O_PO    = O_BQ    + 1536;           // (unused)
constexpr long O_PM    = O_PO    + 409600;
constexpr long O_PL    = O_PM    + 16384;
constexpr long O_PO2   = O_PL    + 16384;          // [3072][1024] CA partials
constexpr long O_PM2   = O_PO2   + 3145728;        // [3072][32]
constexpr long O_PL2   = O_PM2   + 98304;          // [3072][32]
constexpr long O_MS    = O_PL2   + 98304;          // [16][128][128]
constexpr long O_RST   = O_MS    + 262144;         // (unused)
constexpr long O_STATS = O_RST   + 8192;           // [43520][2]
constexpr long O_XH    = O_STATS + 87040;          // [2][1360][8][512] ushort (frag)
constexpr long O_XL    = O_XH    + 5570560;
constexpr long O_SQKVH = O_XL    + 5570560;        // [6][48][8][512] ushort (frag)
constexpr long O_SQKVL = O_SQKVH + 589824;
constexpr long O_SWPH  = O_SQKVL + 589824;         // [6][16][8][512] ushort (frag)
constexpr long O_SWPL  = O_SWPH  + 196608;
constexpr long O_WPH   = O_SWPL  + 196608;         // [6][16][8][512] ushort (frag)
constexpr long O_WPL   = O_WPH   + 196608;
constexpr long WS_FLOATS = O_WPL + 196608;         // ~184 MB

DI int sel4(int4 v, int i) { return i == 0 ? v.x : (i == 1 ? v.y : (i == 2 ? v.z : v.w)); }
DI unsigned short bf_rne(float x) {
  unsigned u = __float_as_uint(x);
  u += 0x7fffu + ((u >> 16) & 1u);
  return (unsigned short)(u >> 16);
}
DI float bf2f(unsigned short h) { return __uint_as_float(((unsigned)h) << 16); }
DI long frag_off(int nblk_base, int k, int n) {
  return ((long)(nblk_base + (n >> 4)) * 8 + (k >> 5)) * 512 +
         ((((k & 31) >> 3)) * 16 + (n & 15)) * 8 + (k & 7);
}

// --- fold LN into KV weights + ca_wq -> FRAGMENT-ORDER split-bf16 -----------
__global__ void fold_w2_kernel(const float* __restrict__ ng, const float* __restrict__ wk,
                               const float* __restrict__ wv, const float* __restrict__ wq,
                               unsigned short* __restrict__ WTh, unsigned short* __restrict__ WTl,
                               unsigned short* __restrict__ WQh, unsigned short* __restrict__ WQl) {
  long idx = (long)blockIdx.x * 256 + threadIdx.x;
  const long T1 = 6L * 512 * 256;
  if (idx < T1) {
    int d = idx / (512 * 256); int r = idx % (512 * 256); int n = r / 256; int k = r % 256;
    float g = ng[d * 256 + k];
    float w = (n < 256) ? wk[((long)(d * 256 + k)) * 256 + n]
                        : wv[((long)(d * 256 + k)) * 256 + (n - 256)];
    w *= g;
    unsigned short hi = bf_rne(w);
    long off = frag_off(d * 32, k, n);
    WTh[off] = hi;
    WTl[off] = bf_rne(w - bf2f(hi));
  } else {
    long j = idx - T1;
    if (j < 6L * 256 * 256) {
      int d = j / 65536; int r = j % 65536; int k = r / 256; int n = r % 256;
      float w = ng[d * 256 + k] * wq[((long)(d * 256 + k)) * 256 + n];
      unsigned short hi = bf_rne(w);
      long off = frag_off(d * 16, k, n);
      WQh[off] = hi;
      WQl[off] = bf_rne(w - bf2f(hi));
    }
  }
}

// --- split sa_wqkv / sa_wp / ca_wp into fragment-order split-bf16 -----------
__global__ void split_wall_kernel(const float* __restrict__ swqkv,
                                  const float* __restrict__ swp,
                                  const float* __restrict__ wp,
                                  unsigned short* __restrict__ SQh, unsigned short* __restrict__ SQl,
                                  unsigned short* __restrict__ SPh, unsigned short* __restrict__ SPl,
                                  unsigned short* __restrict__ WPh, unsigned short* __restrict__ WPl) {
  long idx = (long)blockIdx.x * 256 + threadIdx.x;
  const long T1 = 6L * 256 * 768;
  const long T2 = T1 + 6L * 256 * 256;
  const long T3 = T2 + 6L * 256 * 256;
  if (idx < T1) {
    int d = idx / 196608; int r = idx % 196608; int k = r / 768; int n = r % 768;
    float w = swqkv[idx];
    unsigned short hi = bf_rne(w);
    long off = frag_off(d * 48, k, n);
    SQh[off] = hi;
    SQl[off] = bf_rne(w - bf2f(hi));
  } else if (idx < T2) {
    long j = idx - T1;
    int d = j / 65536; int r = j % 65536; int k = r / 256; int n = r % 256;
    float w = swp[j];
    unsigned short hi = bf_rne(w);
    long off = frag_off(d * 16, k, n);
    SPh[off] = hi;
    SPl[off] = bf_rne(w - bf2f(hi));
  } else if (idx < T3) {
    long j = idx - T2;
    int d = j / 65536; int r = j % 65536; int k = r / 256; int n = r % 256;
    float w = wp[j];
    unsigned short hi = bf_rne(w);
    long off = frag_off(d * 16, k, n);
    WPh[off] = hi;
    WPl[off] = bf_rne(w - bf2f(hi));
  }
}

__global__ void fold_b_kernel(const float* __restrict__ nb, const float* __restrict__ wk,
                              const float* __restrict__ wv, const float* __restrict__ wq,
                              float* __restrict__ bkvo, float* __restrict__ bqo) {
  int idx = blockIdx.x * 256 + threadIdx.x;
  if (idx >= 6 * 768) return;
  int d = idx / 768, j = idx % 768;
  float s = 0.f;
  if (j < 256) {
    for (int c = 0; c < 256; ++c) s = fmaf(nb[d * 256 + c], wk[(d * 256 + c) * 256 + j], s);
    bkvo[d * 512 + j] = s;
  } else if (j < 512) {
    int n = j - 256;
    for (int c = 0; c < 256; ++c) s = fmaf(nb[d * 256 + c], wv[(d * 256 + c) * 256 + n], s);
    bkvo[d * 512 + j] = s;
  } else {
    int n = j - 512;
    for (int c = 0; c < 256; ++c) s = fmaf(nb[d * 256 + c], wq[(d * 256 + c) * 256 + n], s);
    bqo[d * 256 + n] = s;
  }
}

// --- zero the Q pad rows (1600..1631) once ----------------------------------
__global__ void zero_qpad_kernel(unsigned short* __restrict__ Qh,
                                 unsigned short* __restrict__ Ql) {
  int idx = blockIdx.x * 256 + threadIdx.x;
  if (idx < 32 * 256) {
    Qh[1600 * 256 + idx] = 0;
    Ql[1600 * 256 + idx] = 0;
  }
}

// --- per-token LN statistics of feature maps ------------------------------
__global__ __launch_bounds__(256) void ln_stats_kernel(const float* __restrict__ feat,
                                                       float* __restrict__ stats,
                                                       int rowBase, int HW) {
  __shared__ float sred[4][64];
  __shared__ float qred[4][64];
  int b = blockIdx.y, t0 = blockIdx.x * 64;
  int tx = threadIdx.x & 63, ty = threadIdx.x >> 6;
  const float* fb = feat + (long)b * 256 * HW;
  float s = 0.f, q = 0.f;
  for (int k = 0; k < 64; ++k) {
    int c = ty * 64 + k;
    float v = fb[(long)c * HW + t0 + tx];
    s += v; q += v * v;
  }
  sred[ty][tx] = s; qred[ty][tx] = q;
  __syncthreads();
  if (ty == 0) {
    float ts = sred[0][tx] + sred[1][tx] + sred[2][tx] + sred[3][tx];
    float tq = qred[0][tx] + qred[1][tx] + qred[2][tx] + qred[3][tx];
    float m = ts * (1.f / 256.f);
    float var = tq * (1.f / 256.f) - m * m;
    int row = rowBase + b * HW + t0 + tx;
    stats[row * 2 + 0] = m;
    stats[row * 2 + 1] = rsqrtf(var + 1e-5f);
  }
}

// --- build LN-normalized split-bf16 X in FRAGMENT ORDER ---------------------
__global__ __launch_bounds__(256) void ln_split_x_kernel(
    const float* __restrict__ f0, const float* __restrict__ f1,
    const float* __restrict__ f2, const float* __restrict__ f3,
    const float* __restrict__ stats, int vbase,
    unsigned short* __restrict__ Xh, unsigned short* __restrict__ Xl) {
  __shared__ unsigned short Th[64][66], Tl[64][66];
  int m0 = blockIdx.x * 64;
  const float* fp; int HW, rel;
  if (m0 < 16384)      { fp = f0; HW = 4096; rel = m0; }
  else if (m0 < 20480) { fp = f1; HW = 1024; rel = m0 - 16384; }
  else if (m0 < 21504) { fp = f2; HW = 256;  rel = m0 - 20480; }
  else                 { fp = f3; HW = 64;   rel = m0 - 21504; }
  int b = rel / HW, t0 = rel % HW;
  const float* fb = fp + (long)b * 256 * HW + t0;
  int t = threadIdx.x & 63, cg4 = threadIdx.x >> 6;
  float mean = stats[(vbase + m0 + t) * 2 + 0];
  float rstd = stats[(vbase + m0 + t) * 2 + 1];
  long mtb = (long)((vbase + m0) >> 4);
  int lmt = threadIdx.x >> 6, lane = threadIdx.x & 63;
  int fr = lane & 15, g = lane >> 4;
  for (int cgo = 0; cgo < 4; ++cgo) {
    if (cgo) __syncthreads();
#pragma unroll
    for (int i = 0; i < 16; ++i) {
      int c = cgo * 64 + cg4 * 16 + i;
      float x = (fb[(long)c * HW + t] - mean) * rstd;
      unsigned short hi = bf_rne(x);
      Th[t][cg4 * 16 + i] = hi;
      Tl[t][cg4 * 16 + i] = bf_rne(x - bf2f(hi));
    }
    __syncthreads();
#pragma unroll
    for (int sk = 0; sk < 2; ++sk) {
      u16x8 vh = *(const u16x8*)&Th[lmt * 16 + fr][sk * 32 + 8 * g];
      u16x8 vl = *(const u16x8*)&Tl[lmt * 16 + fr][sk * 32 + 8 * g];
      long dst = ((mtb + lmt) * 8 + cgo * 2 + sk) * 512 + lane * 8;
      *(u16x8*)&Xh[dst] = vh;
      *(u16x8*)&Xl[dst] = vl;
    }
  }
}

__global__ void init_q_kernel(const float* __restrict__ qe, float* __restrict__ qb) {
  int idx = blockIdx.x * 256 + threadIdx.x;
  if (idx < 1600 * 256) {
    int row = idx >> 8, c = idx & 255;
    qb[idx] = qe[(row % 100) * 256 + c];
  }
}

// --- generic MFMA projection: C[M,N] = A[M,256] @ W + bias (fp32 out) -------
__global__ __launch_bounds__(256) void gemm_mfma_kernel(
    const float* __restrict__ A,
    const unsigned short* __restrict__ Wh, const unsigned short* __restrict__ Wl,
    const float* __restrict__ bias, float* __restrict__ C, int N) {
  __shared__ unsigned short Ah[2][8][512], Al[2][8][512];
  int n0 = blockIdx.x * 128;
  int m0 = blockIdx.y * 32;
  int tid = threadIdx.x;
  int w = tid >> 6, lane = tid & 63;
  int fr = lane & 15, g = lane >> 4;
#pragma unroll
  for (int mt = 0; mt < 2; ++mt)
#pragma unroll
    for (int kk = 0; kk < 2; ++kk) {
      int ks = 2 * w + kk;
      const float* src = &A[(long)(m0 + mt * 16 + fr) * 256 + ks * 32 + 8 * g];
      float4 f0 = *(const float4*)src;
      float4 f1 = *(const float4*)(src + 4);
      float vals[8] = {f0.x, f0.y, f0.z, f0.w, f1.x, f1.y, f1.z, f1.w};
      union { u16x8 v; unsigned short us[8]; } hh, ll;
#pragma unroll
      for (int e = 0; e < 8; ++e) {
        unsigned short hi = bf_rne(vals[e]);
        hh.us[e] = hi;
        ll.us[e] = bf_rne(vals[e] - bf2f(hi));
      }
      *(u16x8*)&Ah[mt][ks][lane * 8] = hh.v;
      *(u16x8*)&Al[mt][ks][lane * 8] = ll.v;
    }
  __syncthreads();
  f32x4 acc[2][2];
#pragma unroll
  for (int c4 = 0; c4 < 2; ++c4)
#pragma unroll
    for (int mt = 0; mt < 2; ++mt)
#pragma unroll
      for (int r = 0; r < 4; ++r) acc[c4][mt][r] = 0.f;
  for (int ks = 0; ks < 8; ++ks) {
    bf16x8 ah[2], al[2], wh[2], wl[2];
#pragma unroll
    for (int mt = 0; mt < 2; ++mt) {
      ah[mt] = *(const bf16x8*)&Ah[mt][ks][lane * 8];
      al[mt] = *(const bf16x8*)&Al[mt][ks][lane * 8];
    }
#pragma unroll
    for (int c4 = 0; c4 < 2; ++c4) {
      long wb = ((long)((n0 >> 4) + w * 2 + c4) * 8 + ks) * 512 + lane * 8;
      wh[c4] = *(const bf16x8*)&Wh[wb];
      wl[c4] = *(const bf16x8*)&Wl[wb];
    }
#pragma unroll
    for (int c4 = 0; c4 < 2; ++c4)
#pragma unroll
      for (int mt = 0; mt < 2; ++mt) {
        acc[c4][mt] = MFMA16(wh[c4], ah[mt], acc[c4][mt]);
        acc[c4][mt] = MFMA16(wh[c4], al[mt], acc[c4][mt]);
        acc[c4][mt] = MFMA16(wl[c4], ah[mt], acc[c4][mt]);
      }
  }
#pragma unroll
  for (int c4 = 0; c4 < 2; ++c4) {
    int nb = n0 + w * 32 + c4 * 16 + 4 * g;
    float4 bv = make_float4(0.f, 0.f, 0.f, 0.f);
    if (bias) bv = *(const float4*)&bias[nb];
#pragma unroll
    for (int mt = 0; mt < 2; ++mt) {
      int token = m0 + mt * 16 + fr;
      float4 o;
      o.x = acc[c4][mt][0] + bv.x;
      o.y = acc[c4][mt][1] + bv.y;
      o.z = acc[c4][mt][2] + bv.z;
      o.w = acc[c4][mt][3] + bv.w;
      *(float4*)&C[(long)token * N + nb] = o;
    }
  }
}

// --- Q-projection MFMA with INLINE row-LN; emits scaled split-bf16 Qh/Ql ----
__global__ __launch_bounds__(256) void gemm_mfma_qln_kernel(
    const float* __restrict__ A,
    const unsigned short* __restrict__ Wh, const unsigned short* __restrict__ Wl,
    const float* __restrict__ bias,
    unsigned short* __restrict__ Qh, unsigned short* __restrict__ Ql) {
  __shared__ unsigned short Ah[2][8][512], Al[2][8][512];
  __shared__ float part[32][16][2];
  __shared__ float stats[32][2];
  int n0 = blockIdx.x * 128;
  int m0 = blockIdx.y * 32;
  int tid = threadIdx.x;
  int w = tid >> 6, lane = tid & 63;
  int fr = lane & 15, g = lane >> 4;
  const float SC = 0.17677669529663689f;
  float vals[2][16];
#pragma unroll
  for (int mt = 0; mt < 2; ++mt) {
    float s = 0.f, q = 0.f;
#pragma unroll
    for (int kk = 0; kk < 2; ++kk) {
      int ks = 2 * w + kk;
      const float* src = &A[(long)(m0 + mt * 16 + fr) * 256 + ks * 32 + 8 * g];
      float4 f0 = *(const float4*)src;
      float4 f1 = *(const float4*)(src + 4);
      vals[mt][kk * 8 + 0] = f0.x; vals[mt][kk * 8 + 1] = f0.y;
      vals[mt][kk * 8 + 2] = f0.z; vals[mt][kk * 8 + 3] = f0.w;
      vals[mt][kk * 8 + 4] = f1.x; vals[mt][kk * 8 + 5] = f1.y;
      vals[mt][kk * 8 + 6] = f1.z; vals[mt][kk * 8 + 7] = f1.w;
#pragma unroll
      for (int e = 0; e < 8; ++e) {
        float x = vals[mt][kk * 8 + e];
        s += x; q += x * x;
      }
    }
    part[mt * 16 + fr][w * 4 + g][0] = s;
    part[mt * 16 + fr][w * 4 + g][1] = q;
  }
  __syncthreads();
  if (tid < 32) {
    float s = 0.f, q = 0.f;
#pragma unroll
    for (int j = 0; j < 16; ++j) { s += part[tid][j][0]; q += part[tid][j][1]; }
    float mn = s * (1.f / 256.f);
    float var = q * (1.f / 256.f) - mn * mn;
    stats[tid][0] = mn;
    stats[tid][1] = rsqrtf(var + 1e-5f);
  }
  __syncthreads();
#pragma unroll
  for (int mt = 0; mt < 2; ++mt) {
    float mean = stats[mt * 16 + fr][0], rstd = stats[mt * 16 + fr][1];
#pragma unroll
    for (int kk = 0; kk < 2; ++kk) {
      int ks = 2 * w + kk;
      union { u16x8 v; unsigned short us[8]; } hh, ll;
#pragma unroll
      for (int e = 0; e < 8; ++e) {
        float x = (vals[mt][kk * 8 + e] - mean) * rstd;
        unsigned short hi = bf_rne(x);
        hh.us[e] = hi;
        ll.us[e] = bf_rne(x - bf2f(hi));
      }
      *(u16x8*)&Ah[mt][ks][lane * 8] = hh.v;
      *(u16x8*)&Al[mt][ks][lane * 8] = ll.v;
    }
  }
  __syncthreads();
  f32x4 acc[2][2];
#pragma unroll
  for (int c4 = 0; c4 < 2; ++c4)
#pragma unroll
    for (int mt = 0; mt < 2; ++mt)
#pragma unroll
      for (int r = 0; r < 4; ++r) acc[c4][mt][r] = 0.f;
  for (int ks = 0; ks < 8; ++ks) {
    bf16x8 ah[2], al[2], wh[2], wl[2];
#pragma unroll
    for (int mt = 0; mt < 2; ++mt) {
      ah[mt] = *(const bf16x8*)&Ah[mt][ks][lane * 8];
      al[mt] = *(const bf16x8*)&Al[mt][ks][lane * 8];
    }
#pragma unroll
    for (int c4 = 0; c4 < 2; ++c4) {
      long wb = ((long)((n0 >> 4) + w * 2 + c4) * 8 + ks) * 512 + lane * 8;
      wh[c4] = *(const bf16x8*)&Wh[wb];
      wl[c4] = *(const bf16x8*)&Wl[wb];
    }
#pragma unroll
    for (int c4 = 0; c4 < 2; ++c4)
#pragma unroll
      for (int mt = 0; mt < 2; ++mt) {
        acc[c4][mt] = MFMA16(wh[c4], ah[mt], acc[c4][mt]);
        acc[c4][mt] = MFMA16(wh[c4], al[mt], acc[c4][mt]);
        acc[c4][mt] = MFMA16(wl[c4], ah[mt], acc[c4][mt]);
      }
  }
#pragma unroll
  for (int c4 = 0; c4 < 2; ++c4) {
    int nb = n0 + w * 32 + c4 * 16 + 4 * g;
    float4 bv = *(const float4*)&bias[nb];
    float bvs[4] = {bv.x, bv.y, bv.z, bv.w};
#pragma unroll
    for (int mt = 0; mt < 2; ++mt) {
      int token = m0 + mt * 16 + fr;
      ushort4 uh, ul;
#pragma unroll
      for (int r = 0; r < 4; ++r) {
        float val = (acc[c4][mt][r] + bvs[r]) * SC;
        unsigned short hi = bf_rne(val);
        ((unsigned short*)&uh)[r] = hi;
        ((unsigned short*)&ul)[r] = bf_rne(val - bf2f(hi));
      }
      *(ushort4*)&Qh[(long)token * 256 + nb] = uh;
      *(ushort4*)&Ql[(long)token * 256 + nb] = ul;
    }
  }
}

// --- KV projection v8 + XCD-pair swizzle ------------------------------------
__global__ __launch_bounds__(256) void gemm_kv8_kernel(
    const unsigned short* __restrict__ Xh, const unsigned short* __restrict__ Xl,
    const unsigned short* __restrict__ Wh, const unsigned short* __restrict__ Wl,
    const float* __restrict__ bias,
    unsigned short* __restrict__ Kh, unsigned short* __restrict__ Kl,
    unsigned short* __restrict__ VTh, unsigned short* __restrict__ VTl) {
  __shared__ unsigned short Tls[18432];   // K: [64][264], V: [256][72]
  int bid = blockIdx.x;
  int nh = (bid >> 3) & 1;
  int t = (bid & 7) | ((bid >> 4) << 3);   // 0..679
  int v = t / 340;
  int mi = t - v * 340;
  int m0 = mi * 64;
  int tid = threadIdx.x;
  int w = tid >> 6, lane = tid & 63;
  int fr = lane & 15, g = lane >> 4;
  long xmtb = (long)(v * 1360 + mi * 4);
  f32x4 acc[4][4];
#pragma unroll
  for (int c4 = 0; c4 < 4; ++c4)
#pragma unroll
    for (int mt = 0; mt < 4; ++mt)
#pragma unroll
      for (int r = 0; r < 4; ++r) acc[c4][mt][r] = 0.f;
  for (int ks = 0; ks < 8; ++ks) {
    bf16x8 xh_[4], xl_[4], wh_[4], wl_[4];
#pragma unroll
    for (int mt = 0; mt < 4; ++mt) {
      long ar = ((xmtb + mt) * 8 + ks) * 512 + lane * 8;
      xh_[mt] = *(const bf16x8*)&Xh[ar];
      xl_[mt] = *(const bf16x8*)&Xl[ar];
    }
#pragma unroll
    for (int c4 = 0; c4 < 4; ++c4) {
      long br = ((long)(nh * 16 + c4 * 4 + w) * 8 + ks) * 512 + lane * 8;
      wh_[c4] = *(const bf16x8*)&Wh[br];
      wl_[c4] = *(const bf16x8*)&Wl[br];
    }
    if (nh == 0) {
#pragma unroll
      for (int c4 = 0; c4 < 4; ++c4)
#pragma unroll
        for (int mt = 0; mt < 4; ++mt) {
          acc[c4][mt] = MFMA16(wh_[c4], xh_[mt], acc[c4][mt]);
          acc[c4][mt] = MFMA16(wh_[c4], xl_[mt], acc[c4][mt]);
          acc[c4][mt] = MFMA16(wl_[c4], xh_[mt], acc[c4][mt]);
        }
    } else {
#pragma unroll
      for (int c4 = 0; c4 < 4; ++c4)
#pragma unroll
        for (int mt = 0; mt < 4; ++mt) {
          acc[c4][mt] = MFMA16(xh_[mt], wh_[c4], acc[c4][mt]);
          acc[c4][mt] = MFMA16(xl_[mt], wh_[c4], acc[c4][mt]);
          acc[c4][mt] = MFMA16(xh_[mt], wl_[c4], acc[c4][mt]);
        }
    }
  }
  long kvoff = (long)v * KVV;
  long tbb = (long)(m0 >> 5);
  if (nh == 0) {
    for (int part = 0; part < 2; ++part) {
      __syncthreads();
#pragma unroll
      for (int c4 = 0; c4 < 4; ++c4) {
        int nb = c4 * 64 + w * 16 + 4 * g;
        float4 bv4 = *(const float4*)&bias[nb];
        float bvs[4] = {bv4.x, bv4.y, bv4.z, bv4.w};
#pragma unroll
        for (int mt = 0; mt < 4; ++mt) {
          int tok = mt * 16 + fr;
          ushort4 u;
#pragma unroll
          for (int r = 0; r < 4; ++r) {
            float val = acc[c4][mt][r] + bvs[r];
            unsigned short hi = bf_rne(val);
            ((unsigned short*)&u)[r] = (part == 0) ? hi : bf_rne(val - bf2f(hi));
          }
          *(ushort4*)&Tls[tok * 264 + nb] = u;
        }
      }
      __syncthreads();
      unsigned short* dst = (part == 0) ? Kh : Kl;
#pragma unroll
      for (int i = 0; i < 8; ++i) {
        int gid = tid + 256 * i;
        int lane2 = gid & 63;
        int rest = gid >> 6;
        int t16 = rest & 1;
        int h2 = (rest >> 1) & 7;
        int tb_loc = rest >> 4;
        int fr2 = lane2 & 15, g2 = lane2 >> 4;
        int row = tb_loc * 32 + 8 * (fr2 >> 2) + (fr2 & 3) + 4 * t16;
        u16x8 val = *(const u16x8*)&Tls[row * 264 + h2 * 32 + 8 * g2];
        long off = kvoff + (((tbb + tb_loc) * 8 + h2) * 2 + t16) * 512 + lane2 * 8;
        *(u16x8*)&dst[off] = val;
      }
    }
  } else {
    for (int part = 0; part < 2; ++part) {
      __syncthreads();
#pragma unroll
      for (int c4 = 0; c4 < 4; ++c4) {
        int nv = c4 * 64 + w * 16 + fr;
        float bv = bias[256 + nv];
#pragma unroll
        for (int mt = 0; mt < 4; ++mt) {
          int tok = mt * 16 + 4 * g;
          ushort4 u;
#pragma unroll
          for (int r = 0; r < 4; ++r) {
            float val = acc[c4][mt][r] + bv;
            unsigned short hi = bf_rne(val);
            ((unsigned short*)&u)[r] = (part == 0) ? hi : bf_rne(val - bf2f(hi));
          }
          *(ushort4*)&Tls[nv * 72 + tok] = u;
        }
      }
      __syncthreads();
      unsigned short* dst = (part == 0) ? VTh : VTl;
#pragma unroll
      for (int i = 0; i < 8; ++i) {
        int gid = tid + 256 * i;
        int lane2 = gid & 63;
        int rest = gid >> 6;
        int d16 = rest & 1;
        int h2 = (rest >> 1) & 7;
        int tb_loc = rest >> 4;
        int fr2 = lane2 & 15, g2 = lane2 >> 4;
        int row = h2 * 32 + d16 * 16 + fr2;
        int col = tb_loc * 32 + 8 * g2;
        u16x8 val = *(const u16x8*)&Tls[row * 72 + col];
        long off = kvoff + (((tbb + tb_loc) * 8 + h2) * 2 + d16) * 512 + lane2 * 8;
        *(u16x8*)&dst[off] = val;
      }
    }
  }
}

// --- SA flash (VALU path); nc==1 so writes normalized output directly -------
__global__ __launch_bounds__(256) void flash_kernel(const float* __restrict__ qp, int qld,
                                                    const float* __restrict__ kb,
                                                    const float* __restrict__ vb, int kvld,
                                                    int4 startv, int4 nchv, int4 nkv,
                                                    int4 koffv, int4 kstrbv,
                                                    float* __restrict__ outp, int outld) {
  __shared__ float Kt[32][36];
  __shared__ float Vt[32][36];
  int bid = blockIdx.x;
  int s1 = startv.y, s2 = startv.z, s3 = startv.w;
  int l = (bid < s1) ? 0 : (bid < s2) ? 1 : (bid < s3) ? 2 : 3;
  int r = bid - sel4(startv, l);
  int nc = sel4(nchv, l);
  int b = r / (8 * nc);
  int h = (r / nc) & 7;
  int ch = r % nc;
  int Nk = sel4(nkv, l);
  int qr0 = (l * 4 + b) * 100;
  int kr0 = sel4(koffv, l) + b * sel4(kstrbv, l);
  int j0 = ch * 128;
  int jn = min(128, Nk - j0);
  int tiles = (jn + 31) >> 5;
  int tid = threadIdx.x;
  int qi = tid >> 1, half = tid & 1, ho = half * 16, jb = half * 16;
  const float SC = 0.17677669529663689f;
  float4 q8[8];
  if (qi < 100) {
    const float* qrow = qp + (long)(qr0 + qi) * qld + h * 32;
#pragma unroll
    for (int k = 0; k < 8; ++k) {
      float4 f = *(const float4*)&qrow[4 * k];
      q8[k] = make_float4(f.x * SC, f.y * SC, f.z * SC, f.w * SC);
    }
  } else {
#pragma unroll
    for (int k = 0; k < 8; ++k) q8[k] = make_float4(0.f, 0.f, 0.f, 0.f);
  }
  float m = -1e30f, lsum = 0.f;
  float o[16];
#pragma unroll
  for (int i = 0; i < 16; ++i) o[i] = 0.f;

  for (int kt = 0; kt < tiles; ++kt) {
    __syncthreads();
    {
      int rr = tid >> 3, c4 = (tid & 7) * 4;
      int jr = kt * 32 + rr;
      float4 kf = make_float4(0.f, 0.f, 0.f, 0.f), vf = kf;
      if (jr < jn) {
        long g = (long)(kr0 + j0 + jr) * kvld + h * 32 + c4;
        kf = *(const float4*)&kb[g];
        vf = *(const float4*)&vb[g];
      }
      *(float4*)&Kt[rr][c4 ^ (rr & 16)] = kf;
      *(float4*)&Vt[rr][c4] = vf;
    }
    __syncthreads();
    float sv[16];
#pragma unroll
    for (int j = 0; j < 16; ++j) {
      float s = 0.f;
#pragma unroll
      for (int k4 = 0; k4 < 8; ++k4) {
        float4 kv = *(const float4*)&Kt[jb + j][(4 * k4) ^ jb];
        s = fmaf(q8[k4].x, kv.x, s); s = fmaf(q8[k4].y, kv.y, s);
        s = fmaf(q8[k4].z, kv.z, s); s = fmaf(q8[k4].w, kv.w, s);
      }
      int jglob = j0 + kt * 32 + jb + j;
      sv[j] = (jglob < Nk) ? s : -1e30f;
    }
    float tmax = sv[0];
#pragma unroll
    for (int j = 1; j < 16; ++j) tmax = fmaxf(tmax, sv[j]);
    tmax = fmaxf(tmax, __shfl_xor(tmax, 1));
    float mnew = fmaxf(m, tmax);
    float scale = __expf(m - mnew);
    float p[16]; float psum = 0.f;
#pragma unroll
    for (int j = 0; j < 16; ++j) {
      int jglob = j0 + kt * 32 + jb + j;
      float e = (jglob < Nk) ? __expf(sv[j] - mnew) : 0.f;
      p[j] = e; psum += e;
    }
    psum += __shfl_xor(psum, 1);
    lsum = lsum * scale + psum;
    m = mnew;
#pragma unroll
    for (int i = 0; i < 16; ++i) o[i] *= scale;
    float pO[16];
#pragma unroll
    for (int j = 0; j < 16; ++j) pO[j] = __shfl_xor(p[j], 1);
    int jbO = jb ^ 16;
#pragma unroll
    for (int j = 0; j < 16; ++j) {
      float pj = p[j];
      const float* vrow = &Vt[jb + j][ho];
#pragma unroll
      for (int k = 0; k < 4; ++k) {
        float4 v4 = *(const float4*)&vrow[4 * k];
        o[4 * k + 0] = fmaf(pj, v4.x, o[4 * k + 0]);
        o[4 * k + 1] = fmaf(pj, v4.y, o[4 * k + 1]);
        o[4 * k + 2] = fmaf(pj, v4.z, o[4 * k + 2]);
        o[4 * k + 3] = fmaf(pj, v4.w, o[4 * k + 3]);
      }
    }
#pragma unroll
    for (int j = 0; j < 16; ++j) {
      float pj = pO[j];
      const float* vrow = &Vt[jbO + j][ho];
#pragma unroll
      for (int k = 0; k < 4; ++k) {
        float4 v4 = *(const float4*)&vrow[4 * k];
        o[4 * k + 0] = fmaf(pj, v4.x, o[4 * k + 0]);
        o[4 * k + 1] = fmaf(pj, v4.y, o[4 * k + 1]);
        o[4 * k + 2] = fmaf(pj, v4.z, o[4 * k + 2]);
        o[4 * k + 3] = fmaf(pj, v4.w, o[4 * k + 3]);
      }
    }
  }
  if (qi < 100) {
    float inv = 1.f / lsum;
    float* orow = outp + (long)(qr0 + qi) * outld + h * 32 + ho;
#pragma unroll
    for (int k = 0; k < 4; ++k)
      *(float4*)&orow[4 * k] = make_float4(o[4 * k] * inv, o[4 * k + 1] * inv,
                                           o[4 * k + 2] * inv, o[4 * k + 3] * inv);
  }
}

// --- CA flash v3: fully coalesced K'/V' fragment loads ----------------------
__global__ __launch_bounds__(256) void flash_ca2_kernel(
    const unsigned short* __restrict__ Qh, const unsigned short* __restrict__ Ql,
    const unsigned short* __restrict__ Kh, const unsigned short* __restrict__ Kl,
    const unsigned short* __restrict__ VTh, const unsigned short* __restrict__ VTl,
    float* __restrict__ po, float* __restrict__ pm, float* __restrict__ pl) {
  int tid = threadIdx.x;
  int uu = blockIdx.x * 4 + (tid >> 6);
  int v = uu / 1536;
  int u = uu - v * 1536;
  int lane = tid & 63;
  int fr = lane & 15, g = lane >> 4;
  int base, lognc, koff, kstr, ntile, l;
  if (u < 1024)      { base = 0;    lognc = 3; koff = 0;     kstr = 4096; ntile = 16; l = 0; }
  else if (u < 1280) { base = 1024; lognc = 1; koff = 16384; kstr = 1024; ntile = 16; l = 1; }
  else if (u < 1408) { base = 1280; lognc = 0; koff = 20480; kstr = 256;  ntile = 8;  l = 2; }
  else               { base = 1408; lognc = 0; koff = 21504; kstr = 64;   ntile = 2;  l = 3; }
  int r = u - base;
  int qg = r & 3; r >>= 2;
  int ch = r & ((1 << lognc) - 1); r >>= lognc;
  int h = r & 7, b = r >> 3;
  long kvoff = (long)v * KVV;
  long qoff = ((long)((l * 4 + b) * 100 + qg * 32)) * 256 + h * 32 + 8 * g;
  bf16x8 qh0 = *(const bf16x8*)&Qh[qoff + fr * 256];
  bf16x8 qh1 = *(const bf16x8*)&Qh[qoff + (16 + fr) * 256];
  bf16x8 ql0 = *(const bf16x8*)&Ql[qoff + fr * 256];
  bf16x8 ql1 = *(const bf16x8*)&Ql[qoff + (16 + fr) * 256];
  int tb0 = (koff + b * kstr + ch * 512) >> 5;
  f32x4 o00 = {0.f, 0.f, 0.f, 0.f}, o01 = o00, o10 = o00, o11 = o00;
  float m0r = -1e30f, m1r = -1e30f, l0r = 0.f, l1r = 0.f;

  for (int kt = 0; kt < ntile; ++kt) {
    long fb = kvoff + (((long)(tb0 + kt) * 8 + h) * 2) * 512 + lane * 8;
    bf16x8 kh0 = *(const bf16x8*)&Kh[fb];
    bf16x8 kl0 = *(const bf16x8*)&Kl[fb];
    bf16x8 kh1 = *(const bf16x8*)&Kh[fb + 512];
    bf16x8 kl1 = *(const bf16x8*)&Kl[fb + 512];
    bf16x8 vh0 = *(const bf16x8*)&VTh[fb];
    bf16x8 vl0 = *(const bf16x8*)&VTl[fb];
    bf16x8 vh1 = *(const bf16x8*)&VTh[fb + 512];
    bf16x8 vl1 = *(const bf16x8*)&VTl[fb + 512];
    f32x4 zz = {0.f, 0.f, 0.f, 0.f};
    f32x4 s00 = zz, s01 = zz, s10 = zz, s11 = zz;
    s00 = MFMA16(kh0, qh0, s00); s00 = MFMA16(kl0, qh0, s00); s00 = MFMA16(kh0, ql0, s00);
    s01 = MFMA16(kh1, qh0, s01); s01 = MFMA16(kl1, qh0, s01); s01 = MFMA16(kh1, ql0, s01);
    s10 = MFMA16(kh0, qh1, s10); s10 = MFMA16(kl0, qh1, s10); s10 = MFMA16(kh0, ql1, s10);
    s11 = MFMA16(kh1, qh1, s11); s11 = MFMA16(kl1, qh1, s11); s11 = MFMA16(kh1, ql1, s11);
    {
      float t0 = fmaxf(fmaxf(s00[0], s00[1]), fmaxf(s00[2], s00[3]));
      float t1 = fmaxf(fmaxf(s01[0], s01[1]), fmaxf(s01[2], s01[3]));
      float tm = fmaxf(t0, t1);
      tm = fmaxf(tm, __shfl_xor(tm, 16));
      tm = fmaxf(tm, __shfl_xor(tm, 32));
      float mn = fmaxf(m0r, tm);
      float sc = __expf(m0r - mn); m0r = mn;
      float p[8]; float ps = 0.f;
#pragma unroll
      for (int i = 0; i < 4; ++i) { p[i] = __expf(s00[i] - mn); ps += p[i]; }
#pragma unroll
      for (int i = 0; i < 4; ++i) { p[4 + i] = __expf(s01[i] - mn); ps += p[4 + i]; }
      l0r = l0r * sc + ps;
      union { bf16x8 v; unsigned short us[8]; } ph, plo;
#pragma unroll
      for (int e = 0; e < 8; ++e) {
        unsigned short hi = bf_rne(p[e]);
        ph.us[e] = hi;
        plo.us[e] = bf_rne(p[e] - bf2f(hi));
      }
#pragma unroll
      for (int i = 0; i < 4; ++i) { o00[i] *= sc; o01[i] *= sc; }
      o00 = MFMA16(vh0, ph.v, o00); o00 = MFMA16(vl0, ph.v, o00); o00 = MFMA16(vh0, plo.v, o00);
      o01 = MFMA16(vh1, ph.v, o01); o01 = MFMA16(vl1, ph.v, o01); o01 = MFMA16(vh1, plo.v, o01);
    }
    {
      float t0 = fmaxf(fmaxf(s10[0], s10[1]), fmaxf(s10[2], s10[3]));
      float t1 = fmaxf(fmaxf(s11[0], s11[1]), fmaxf(s11[2], s11[3]));
      float tm = fmaxf(t0, t1);
      tm = fmaxf(tm, __shfl_xor(tm, 16));
      tm = fmaxf(tm, __shfl_xor(tm, 32));
      float mn = fmaxf(m1r, tm);
      float sc = __expf(m1r - mn); m1r = mn;
      float p[8]; float ps = 0.f;
#pragma unroll
      for (int i = 0; i < 4; ++i) { p[i] = __expf(s10[i] - mn); ps += p[i]; }
#pragma unroll
      for (int i = 0; i < 4; ++i) { p[4 + i] = __expf(s11[i] - mn); ps += p[4 + i]; }
      l1r = l1r * sc + ps;
      union { bf16x8 v; unsigned short us[8]; } ph, plo;
#pragma unroll
      for (int e = 0; e < 8; ++e) {
        unsigned short hi = bf_rne(p[e]);
        ph.us[e] = hi;
        plo.us[e] = bf_rne(p[e] - bf2f(hi));
      }
#pragma unroll
      for (int i = 0; i < 4; ++i) { o10[i] *= sc; o11[i] *= sc; }
      o10 = MFMA16(vh0, ph.v, o10); o10 = MFMA16(vl0, ph.v, o10); o10 = MFMA16(vh0, plo.v, o10);
      o11 = MFMA16(vh1, ph.v, o11); o11 = MFMA16(vl1, ph.v, o11); o11 = MFMA16(vh1, plo.v, o11);
    }
  }
  l0r += __shfl_xor(l0r, 16); l0r += __shfl_xor(l0r, 32);
  l1r += __shfl_xor(l1r, 16); l1r += __shfl_xor(l1r, 32);
  long pob = (long)uu * 1024;
  *(f32x4*)&po[pob + fr * 32 + 4 * g] = o00;
  *(f32x4*)&po[pob + fr * 32 + 16 + 4 * g] = o01;
  *(f32x4*)&po[pob + (16 + fr) * 32 + 4 * g] = o10;
  *(f32x4*)&po[pob + (16 + fr) * 32 + 16 + 4 * g] = o11;
  if (g == 0) {
    pm[uu * 32 + fr] = m0r;       pl[uu * 32 + fr] = l0r;
    pm[uu * 32 + 16 + fr] = m1r;  pl[uu * 32 + 16 + fr] = l1r;
  }
}

// --- CA combine v2 (both views): unit = (v,l,b,h,qg), 1024 blocks -----------
__global__ __launch_bounds__(256) void combine2_kernel(const float* __restrict__ po,
                                                       const float* __restrict__ pm,
                                                       const float* __restrict__ pl,
                                                       float* __restrict__ oca) {
  int gu = blockIdx.x;
  int v = gu >> 9;
  int u = gu & 511;
  int l = u >> 7, ur = u & 127;
  int b = ur >> 5, h = (ur >> 2) & 7, qg = ur & 3;
  int nc, base;
  if (l == 0)      { nc = 8; base = 0; }
  else if (l == 1) { nc = 2; base = 1024; }
  else if (l == 2) { nc = 1; base = 1280; }
  else             { nc = 1; base = 1408; }
  int pu0 = v * 1536 + base + ((b * 8 + h) * nc) * 4 + qg;
  int qr0 = (l * 4 + b) * 100 + qg * 32;
  int qn = min(32, 100 - qg * 32);
  float* outp = oca + (long)v * 409600;
  for (int e = threadIdx.x; e < 1024; e += 256) {
    int qi = e >> 5, d = e & 31;
    if (qi >= qn) continue;
    float mstar = -1e30f;
    for (int c = 0; c < nc; ++c) mstar = fmaxf(mstar, pm[(pu0 + 4 * c) * 32 + qi]);
    float Lt = 0.f, val = 0.f;
    for (int c = 0; c < nc; ++c) {
      float w = __expf(pm[(pu0 + 4 * c) * 32 + qi] - mstar);
      Lt = fmaf(w, pl[(pu0 + 4 * c) * 32 + qi], Lt);
      val = fmaf(w, po[(long)(pu0 + 4 * c) * 1024 + qi * 32 + d], val);
    }
    outp[(long)(qr0 + qi) * 256 + h * 32 + d] = val / Lt;
  }
}

// --- ms = q1 @ q2^T ---------------------------------------------------------
DI float dot4(float4 a, float4 b) {
  float s = a.x * b.x;
  s = fmaf(a.y, b.y, s); s = fmaf(a.z, b.z, s); s = fmaf(a.w, b.w, s);
  return s;
}
__global__ __launch_bounds__(256) void fuse_ms_kernel(const float* __restrict__ q1,
                                                      const float* __restrict__ q2,
                                                      float* __restrict__ ms) {
  __shared__ float a[32][132];
  __shared__ float bsh[32][132];
  int lb = blockIdx.x;
  int it = blockIdx.y >> 2, jt = blockIdx.y & 3;
  int tid = threadIdx.x;
  int ti = tid & 15, tj = tid >> 4;
  float acc[2][2] = {};
  for (int chalf = 0; chalf < 2; ++chalf) {
    __syncthreads();
#pragma unroll
    for (int k = 0; k < 4; ++k) {
      int i = tid + k * 256;
      int rr = i >> 5, c4 = (i & 31) * 4;
      int row1 = it * 32 + rr, row2 = jt * 32 + rr;
      float4 fa = make_float4(0.f, 0.f, 0.f, 0.f), fb = fa;
      if (row1 < 100) fa = *(const float4*)&q1[(long)(lb * 100 + row1) * 256 + chalf * 128 + c4];
      if (row2 < 100) fb = *(const float4*)&q2[(long)(lb * 100 + row2) * 256 + chalf * 128 + c4];
      *(float4*)&a[rr][c4] = fa;
      *(float4*)&bsh[rr][c4] = fb;
    }
    __syncthreads();
#pragma unroll
    for (int k4 = 0; k4 < 32; ++k4) {
      float4 a0 = *(const float4*)&a[2 * ti][4 * k4];
      float4 a1 = *(const float4*)&a[2 * ti + 1][4 * k4];
      float4 b0 = *(const float4*)&bsh[2 * tj][4 * k4];
      float4 b1 = *(const float4*)&bsh[2 * tj + 1][4 * k4];
      acc[0][0] += dot4(a0, b0); acc[0][1] += dot4(a0, b1);
      acc[1][0] += dot4(a1, b0); acc[1][1] += dot4(a1, b1);
    }
  }
#pragma unroll
  for (int i = 0; i < 2; ++i)
#pragma unroll
    for (int j = 0; j < 2; ++j)
      ms[(long)(lb * 128 + it * 32 + 2 * ti + i) * 128 + jt * 32 + 2 * tj + j] = acc[i][j];
}

// --- r1/r2 mixing + channel softmax, stats computed INLINE ------------------
__global__ __launch_bounds__(256) void fuse_apply_kernel(const float* __restrict__ ms,
                                                         const float* __restrict__ q1,
                                                         const float* __restrict__ q2,
                                                         const float* __restrict__ qsa,
                                                         float* __restrict__ qout) {
  __shared__ float pr[128], pc[128];
  __shared__ float red[8];
  __shared__ float red1[4], red2[4];
  int lb = blockIdx.x, i = blockIdx.y, tid = threadIdx.x;
  long r = lb * 100 + i;
  if (tid < 128)
    pr[tid] = (tid < 100) ? ms[(long)(lb * 128 + i) * 128 + tid] : -1e30f;
  else
    pc[tid - 128] = (tid < 228) ? ms[(long)(lb * 128 + (tid - 128)) * 128 + i] : -1e30f;
  __syncthreads();
  if (tid < 64) {
    float mx = fmaxf(pr[tid], pr[tid + 64]);
    for (int o = 32; o; o >>= 1) mx = fmaxf(mx, __shfl_xor(mx, o));
    if (tid == 0) red[0] = mx;
  } else if (tid >= 128 && tid < 192) {
    int t2 = tid - 128;
    float mx = fmaxf(pc[t2], pc[t2 + 64]);
    for (int o = 32; o; o >>= 1) mx = fmaxf(mx, __shfl_xor(mx, o));
    if (t2 == 0) red[2] = mx;
  }
  __syncthreads();
  float rm = red[0], cm = red[2];
  if (tid < 128)
    pr[tid] = (tid < 100) ? __expf(pr[tid] - rm) : 0.f;
  else
    pc[tid - 128] = (tid < 228) ? __expf(pc[tid - 128] - cm) : 0.f;
  __syncthreads();
  if (tid < 64) {
    float sm = pr[tid] + pr[tid + 64];
    for (int o = 32; o; o >>= 1) sm += __shfl_xor(sm, o);
    if (tid == 0) red[1] = sm;
  } else if (tid >= 128 && tid < 192) {
    int t2 = tid - 128;
    float sm = pc[t2] + pc[t2 + 64];
    for (int o = 32; o; o >>= 1) sm += __shfl_xor(sm, o);
    if (t2 == 0) red[3] = sm;
  }
  __syncthreads();
  float rs = red[1], cs = red[3];
  float acc1 = 0.f, acc2 = 0.f;
  for (int j = 0; j < 100; ++j) acc1 = fmaf(pr[j], q2[(long)(lb * 100 + j) * 256 + tid], acc1);
  for (int j = 0; j < 100; ++j) acc2 = fmaf(pc[j], q1[(long)(lb * 100 + j) * 256 + tid], acc2);
  acc1 /= rs;
  acc2 /= cs;
  float z = qsa[r * 256 + tid] + q1[r * 256 + tid] + acc1 + q2[r * 256 + tid] + acc2;
  float v = z;
  for (int off = 32; off; off >>= 1) v = fmaxf(v, __shfl_xor(v, off));
  int w = tid >> 6;
  if ((tid & 63) == 0) red1[w] = v;
  __syncthreads();
  float zm = fmaxf(fmaxf(red1[0], red1[1]), fmaxf(red1[2], red1[3]));
  float e = __expf(z - zm);
  float sv = e;
  for (int off = 32; off; off >>= 1) sv += __shfl_xor(sv, off);
  if ((tid & 63) == 0) red2[w] = sv;
  __syncthreads();
  float es = red2[0] + red2[1] + red2[2] + red2[3];
  qout[r * 256 + tid] = e / es;
}

// ---------------------------------------------------------------------------
extern "C" void kernel_launch(void* const* d_in, const int* in_sizes, int n_in,
                              void* d_out, int out_size, void* d_ws, size_t ws_size,
                              hipStream_t stream) {
  (void)in_sizes; (void)n_in; (void)out_size; (void)ws_size;
  const float* feats[2][4] = {
      {(const float*)d_in[0], (const float*)d_in[1], (const float*)d_in[2], (const float*)d_in[3]},
      {(const float*)d_in[4], (const float*)d_in[5], (const float*)d_in[6], (const float*)d_in[7]}};
  const float* qe   = (const float*)d_in[8];
  const float* ng   = (const float*)d_in[9];
  const float* nb   = (const float*)d_in[10];
  const float* wq   = (const float*)d_in[11];
  const float* wk   = (const float*)d_in[12];
  const float* wv   = (const float*)d_in[13];
  const float* wp   = (const float*)d_in[14];
  const float* bp   = (const float*)d_in[15];
  const float* swqkv= (const float*)d_in[16];
  const float* swp  = (const float*)d_in[17];
  const float* sbp  = (const float*)d_in[18];

  float* ws = (float*)d_ws;
  unsigned short* KHp  = (unsigned short*)(ws + O_KH);
  unsigned short* KLp  = (unsigned short*)(ws + O_KL);
  unsigned short* VTHp = (unsigned short*)(ws + O_VTH);
  unsigned short* VTLp = (unsigned short*)(ws + O_VTL);
  float* QBUFp = ws + O_QBUF;
  float* QKVp  = ws + O_QKV;
  float* QSAp  = ws + O_QSA;
  float* SAOp  = ws + O_SAO;
  float* OCAp  = ws + O_OCA;
  float* Q12p  = ws + O_Q12;
  unsigned short* QHp  = (unsigned short*)(ws + O_QH);
  unsigned short* QLp  = (unsigned short*)(ws + O_QL);
  unsigned short* WTHp = (unsigned short*)(ws + O_WTH);
  unsigned short* WTLp = (unsigned short*)(ws + O_WTL);
  unsigned short* WQHp = (unsigned short*)(ws + O_WQH);
  unsigned short* WQLp = (unsigned short*)(ws + O_WQL);
  float* BKVp  = ws + O_BKV;
  float* BQp   = ws + O_BQ;
  float* PO2p  = ws + O_PO2;
  float* PM2p  = ws + O_PM2;
  float* PL2p  = ws + O_PL2;
  float* MSp   = ws + O_MS;
  float* STATSp= ws + O_STATS;
  unsigned short* XHp  = (unsigned short*)(ws + O_XH);
  unsigned short* XLp  = (unsigned short*)(ws + O_XL);
  unsigned short* SQHp = (unsigned short*)(ws + O_SQKVH);
  unsigned short* SQLp = (unsigned short*)(ws + O_SQKVL);
  unsigned short* SPHp = (unsigned short*)(ws + O_SWPH);
  unsigned short* SPLp = (unsigned short*)(ws + O_SWPL);
  unsigned short* WPHp = (unsigned short*)(ws + O_WPH);
  unsigned short* WPLp = (unsigned short*)(ws + O_WPL);

  const int HWs[4] = {4096, 1024, 256, 64};
  const int VOs[4] = {0, 16384, 20480, 21504};

  fold_w2_kernel<<<4608, 256, 0, stream>>>(ng, wk, wv, wq, WTHp, WTLp, WQHp, WQLp);
  split_wall_kernel<<<7680, 256, 0, stream>>>(swqkv, swp, wp, SQHp, SQLp, SPHp, SPLp, WPHp, WPLp);
  fold_b_kernel<<<18, 256, 0, stream>>>(nb, wk, wv, wq, BKVp, BQp);
  zero_qpad_kernel<<<32, 256, 0, stream>>>(QHp, QLp);
  for (int v = 0; v < 2; ++v)
    for (int l = 0; l < 4; ++l)
      ln_stats_kernel<<<dim3(HWs[l] / 64, 4), 256, 0, stream>>>(
          feats[v][l], STATSp, v * 21760 + VOs[l], HWs[l]);
  for (int v = 0; v < 2; ++v)
    ln_split_x_kernel<<<340, 256, 0, stream>>>(
        feats[v][0], feats[v][1], feats[v][2], feats[v][3], STATSp, v * 21760, XHp, XLp);
  init_q_kernel<<<1600, 256, 0, stream>>>(qe, QBUFp);

  const int4 saStart = make_int4(0, 32, 64, 96);
  const int4 saNch   = make_int4(1, 1, 1, 1);
  const int4 saNk    = make_int4(100, 100, 100, 100);
  const int4 saKoff  = make_int4(0, 400, 800, 1200);
  const int4 saKstrb = make_int4(100, 100, 100, 100);

  for (int d = 0; d < 6; ++d) {
    // --- self attention (flash writes normalized output directly) ---
    gemm_mfma_kernel<<<dim3(6, 50), 256, 0, stream>>>(
        QBUFp, SQHp + (long)d * 196608, SQLp + (long)d * 196608, nullptr, QKVp, 768);
    flash_kernel<<<128, 256, 0, stream>>>(QKVp, 768, QKVp + 256, QKVp + 512, 768,
                                          saStart, saNch, saNk, saKoff, saKstrb, SAOp, 256);
    gemm_mfma_kernel<<<dim3(2, 50), 256, 0, stream>>>(
        SAOp, SPHp + (long)d * 65536, SPLp + (long)d * 65536, sbp + d * 256, QSAp, 256);
    // --- cross-attention query projection (LN + scale + split fused) ---
    gemm_mfma_qln_kernel<<<dim3(2, 50), 256, 0, stream>>>(
        QSAp, WQHp + (long)d * 65536, WQLp + (long)d * 65536, BQp + d * 256, QHp, QLp);
    // --- cross attention, both views per dispatch ---
    gemm_kv8_kernel<<<1360, 256, 0, stream>>>(
        XHp, XLp, WTHp + (long)d * 131072, WTLp + (long)d * 131072, BKVp + d * 512,
        KHp, KLp, VTHp, VTLp);
    flash_ca2_kernel<<<768, 256, 0, stream>>>(QHp, QLp, KHp, KLp, VTHp, VTLp,
                                              PO2p, PM2p, PL2p);
    combine2_kernel<<<1024, 256, 0, stream>>>(PO2p, PM2p, PL2p, OCAp);
    gemm_mfma_kernel<<<dim3(2, 100), 256, 0, stream>>>(
        OCAp, WPHp + (long)d * 65536, WPLp + (long)d * 65536, bp + d * 256, Q12p, 256);
    // --- matching fusion + channel softmax (stats inline) ---
    fuse_ms_kernel<<<dim3(16, 16), 256, 0, stream>>>(Q12p, Q12p + 409600, MSp);
    fuse_apply_kernel<<<dim3(16, 100), 256, 0, stream>>>(MSp, Q12p, Q12p + 409600,
                                                         QSAp, QBUFp);
  }
  hipMemcpyAsync(d_out, QBUFp, 409600 * sizeof(float), hipMemcpyDeviceToDevice, stream);
}